// Round 11
// baseline (209.921 us; speedup 1.0000x reference)
//
#include <hip/hip_runtime.h>
#include <hip/hip_bf16.h>
#include <hip/hip_fp16.h>

// GCN forward: 2x GCNConv(relu) -> global_mean_pool -> MLP head.
// Round 11 (= round 10 + compile fix): mean-pool fused into layer-2 gather
//          (bufB eliminated); x16 prep fused into bucket_process; 9 launches.
//          Fix: int-typed clamp for batch[] index (min() overload ambiguity).

#define HIDC 64
#define MTILE 128
#define XS_STRIDE (MTILE + 4)
#define BSHIFT 9
#define SPAN 512          // nodes per bucket
#define NBKT_MAX 256      // requires N <= 131072
#define BCHUNK 2048       // edges per workgroup in k_bin_scatter
#define MAXSEG 4          // LDS pool segments per 32-node window (fallback if exceeded)

typedef unsigned long long u64;

// zero bucket_cnt (NB ints) + pooled/cnt (G*65 floats, contiguous)
__global__ void k_init(int* bucket_cnt, int nb, float* pooled, int npool) {
    int i = blockIdx.x * blockDim.x + threadIdx.x;
    if (i < nb) bucket_cnt[i] = 0;
    if (i < npool) pooled[i] = 0.f;
}

// per-workgroup LDS histogram of edge destinations by bucket
__global__ __launch_bounds__(256) void k_bin_count(const int* __restrict__ col,
                                                   int* bucket_cnt, int E, int NB) {
    __shared__ int hist[NBKT_MAX];
    int tid = threadIdx.x;
    for (int i = tid; i < NB; i += 256) hist[i] = 0;
    __syncthreads();
    int base = blockIdx.x * 8192;
    for (int j = 0; j < 32; ++j) {
        int e = base + j * 256 + tid;
        if (e < E) atomicAdd(&hist[col[e] >> BSHIFT], 1);
    }
    __syncthreads();
    for (int i = tid; i < NB; i += 256)
        if (hist[i]) atomicAdd(&bucket_cnt[i], hist[i]);
}

// exclusive scan of bucket counts (NB <= 256); emits base + cursor copy
__global__ void k_bucket_scan(const int* __restrict__ bucket_cnt, int* __restrict__ bucket_base,
                              int* __restrict__ cursor_g, int NB, int E) {
    __shared__ int s[256];
    int t = threadIdx.x;
    int v = (t < NB) ? bucket_cnt[t] : 0;
    s[t] = v;
    __syncthreads();
    for (int o = 1; o < 256; o <<= 1) {
        int x = (t >= o) ? s[t - o] : 0;
        __syncthreads();
        s[t] += x;
        __syncthreads();
    }
    if (t < NB) { int ex = s[t] - v; bucket_base[t] = ex; cursor_g[t] = ex; }
    if (t == 0) bucket_base[NB] = E;
}

// partition edges into destination buckets via LDS staging; flushes are
// contiguous runs per bucket (coalesced). packed = ew(32) | src(23) | colin(9).
__global__ __launch_bounds__(256) void k_bin_scatter(const int* __restrict__ row,
                                                     const int* __restrict__ col,
                                                     const float* __restrict__ ew,
                                                     int* cursor_g, u64* __restrict__ bedges,
                                                     int E, int NB) {
    __shared__ int hist[NBKT_MAX], binoff[NBKT_MAX], cursor[NBKT_MAX], gbase[NBKT_MAX];
    __shared__ int s[256];
    __shared__ u64 stage[BCHUNK];
    __shared__ unsigned char binid[BCHUNK];
    int tid = threadIdx.x;
    for (int i = tid; i < NB; i += 256) hist[i] = 0;
    __syncthreads();
    int base = blockIdx.x * BCHUNK;
    u64 pk[8]; int bb[8];
#pragma unroll
    for (int j = 0; j < 8; ++j) {
        int e = base + j * 256 + tid;
        if (e < E) {
            int c = col[e];
            bb[j] = c >> BSHIFT;
            pk[j] = ((u64)__float_as_uint(ew[e]) << 32) |
                    ((u64)(unsigned)row[e] << BSHIFT) | (unsigned)(c & (SPAN - 1));
            atomicAdd(&hist[bb[j]], 1);
        } else bb[j] = -1;
    }
    __syncthreads();
    {   // exclusive scan of hist -> binoff
        int v = (tid < NB) ? hist[tid] : 0;
        s[tid] = v;
        __syncthreads();
        for (int o = 1; o < 256; o <<= 1) {
            int x = (tid >= o) ? s[tid - o] : 0;
            __syncthreads();
            s[tid] += x;
            __syncthreads();
        }
        if (tid < NB) { binoff[tid] = s[tid] - v; cursor[tid] = s[tid] - v; }
    }
    __syncthreads();
#pragma unroll
    for (int j = 0; j < 8; ++j)
        if (bb[j] >= 0) {
            int pos = atomicAdd(&cursor[bb[j]], 1);
            stage[pos] = pk[j];
            binid[pos] = (unsigned char)bb[j];
        }
    __syncthreads();
    if (tid < NB && hist[tid] > 0) gbase[tid] = atomicAdd(&cursor_g[tid], hist[tid]);
    __syncthreads();
    int total = min(BCHUNK, E - base);
    for (int i = tid; i < total; i += 256) {
        int b = binid[i];
        bedges[(size_t)gbase[b] + (i - binoff[b])] = stage[i];
    }
}

// one workgroup per bucket: LDS degree accumulate, scan -> CSR offsets,
// in-bucket scatter, emit dinv + off + scaled fp16 x-rows (prep fused).
__global__ __launch_bounds__(256) void k_bucket_process(const u64* __restrict__ bedges,
                                                        const int* __restrict__ bucket_base,
                                                        const float* __restrict__ x,
                                                        u64* __restrict__ csr,
                                                        float* __restrict__ dinv,
                                                        int* __restrict__ off,
                                                        __half* __restrict__ x16,
                                                        int N, int E, int NB, int K) {
    __shared__ float deg[SPAN];
    __shared__ int cL[SPAN];
    __shared__ int offL[SPAN];
    __shared__ int s[256];
    int b = blockIdx.x, tid = threadIdx.x;
    int ebase = bucket_base[b], ecnt = bucket_base[b + 1] - ebase;
    int nd0 = b << BSHIFT;
    int ndn = min(SPAN, N - nd0);
    for (int i = tid; i < SPAN; i += 256) { deg[i] = 1.0f; cL[i] = 0; }
    __syncthreads();
    for (int e = tid; e < ecnt; e += 256) {
        u64 p = bedges[ebase + e];
        int colin = (int)(p & (SPAN - 1));
        atomicAdd(&deg[colin], __uint_as_float((unsigned)(p >> 32)));
        atomicAdd(&cL[colin], 1);
    }
    __syncthreads();
    // exclusive scan of cL[0..SPAN) via pairs (SPAN = 2*256)
    int p0 = cL[2 * tid], p1 = cL[2 * tid + 1];
    s[tid] = p0 + p1;
    __syncthreads();
    for (int o = 1; o < 256; o <<= 1) {
        int x_ = (tid >= o) ? s[tid - o] : 0;
        __syncthreads();
        s[tid] += x_;
        __syncthreads();
    }
    int ex = s[tid] - (p0 + p1);
    offL[2 * tid] = ex;
    offL[2 * tid + 1] = ex + p0;
    __syncthreads();
    for (int i = tid; i < ndn; i += 256) {
        float dv = rsqrtf(deg[i]);
        deg[i] = dv;                       // keep dinv in LDS for the x16 pass
        dinv[nd0 + i] = dv;
        off[nd0 + i] = ebase + offL[i];
    }
    for (int i = tid; i < SPAN; i += 256) cL[i] = offL[i];   // cursors
    if (b == NB - 1 && tid == 0) off[N] = E;
    __syncthreads();
    // CSR scatter within bucket (L2-resident region)
    for (int e = tid; e < ecnt; e += 256) {
        u64 p = bedges[ebase + e];
        int colin = (int)(p & (SPAN - 1));
        int src = (int)((p >> BSHIFT) & 0x7FFFFF);   // 23 bits
        int slot = atomicAdd(&cL[colin], 1);
        csr[(size_t)ebase + slot] = ((u64)(unsigned)src << 32) | (unsigned)(p >> 32);
    }
    // fused prep: x16[node][32] = fp16(dinv*x[node][0..K)), rest zero (64B rows)
    for (int i = tid; i < ndn * 16; i += 256) {
        int nl = i >> 4, p = i & 15, c0 = p * 2;
        float dv = deg[nl];
        const float* xr = x + (size_t)(nd0 + nl) * K;
        float a = (c0 < K)     ? dv * xr[c0]     : 0.f;
        float bq = (c0 + 1 < K) ? dv * xr[c0 + 1] : 0.f;
        reinterpret_cast<__half2*>(x16)[(size_t)(nd0 + nl) * 16 + p] = __floats2half2_rn(a, bq);
    }
}

// Layer-1 aggregation over raw x: 8 nodes/wave (8 lanes each, uint2 = 4ch/lane),
// 8-wide edge unroll -> up to 64 row fetches in flight per wave.
__global__ void k_agg_x(const __half* __restrict__ x16, const int* __restrict__ off,
                        const u64* __restrict__ csr, const float* __restrict__ dinv,
                        float* __restrict__ agg, int n, int K) {
    int t = blockIdx.x * blockDim.x + threadIdx.x;
    int lane = threadIdx.x & 63;
    int node = ((t >> 6) << 3) + (lane >> 3);   // 8 nodes per wave
    int sub = lane & 7;                         // uint2 index (4 channels)
    if (node >= n) return;
    const uint2* xp = reinterpret_cast<const uint2*>(x16);   // 8 uint2 per row
    uint2 sv = xp[(size_t)node * 8 + sub];
    float acc0, acc1, acc2, acc3;
    {
        float2 a = __half22float2(*(const __half2*)&sv.x);
        float2 b = __half22float2(*(const __half2*)&sv.y);
        acc0 = a.x; acc1 = a.y; acc2 = b.x; acc3 = b.y;
    }
    int i = off[node], e1 = off[node + 1];
    for (; i + 7 < e1; i += 8) {
        u64 e[8]; uint2 r[8];
#pragma unroll
        for (int j = 0; j < 8; ++j) e[j] = csr[i + j];
#pragma unroll
        for (int j = 0; j < 8; ++j) r[j] = xp[(size_t)(e[j] >> 32) * 8 + sub];
#pragma unroll
        for (int j = 0; j < 8; ++j) {
            float w = __uint_as_float((unsigned)e[j]);
            float2 a = __half22float2(*(const __half2*)&r[j].x);
            float2 b = __half22float2(*(const __half2*)&r[j].y);
            acc0 = fmaf(w, a.x, acc0); acc1 = fmaf(w, a.y, acc1);
            acc2 = fmaf(w, b.x, acc2); acc3 = fmaf(w, b.y, acc3);
        }
    }
    for (; i < e1; ++i) {
        u64 e0 = csr[i];
        uint2 r = xp[(size_t)(e0 >> 32) * 8 + sub];
        float w = __uint_as_float((unsigned)e0);
        float2 a = __half22float2(*(const __half2*)&r.x);
        float2 b = __half22float2(*(const __half2*)&r.y);
        acc0 = fmaf(w, a.x, acc0); acc1 = fmaf(w, a.y, acc1);
        acc2 = fmaf(w, b.x, acc2); acc3 = fmaf(w, b.y, acc3);
    }
    int c0 = sub * 4;
    float d = dinv[node];
    float* ap = agg + (size_t)node * K + c0;
    if (c0 + 3 < K) {
        float2 o0; o0.x = d * acc0; o0.y = d * acc1;
        float2 o1; o1.x = d * acc2; o1.y = d * acc3;
        *reinterpret_cast<float2*>(ap) = o0;
        *reinterpret_cast<float2*>(ap + 2) = o1;
    } else if (c0 < K) {   // K=22: c0==20 -> last 2 channels
        float2 o; o.x = d * acc0; o.y = d * acc1;
        *reinterpret_cast<float2*>(ap) = o;
    }
}

// Fused layer-1 transform: hbuf = fp16(dinv * (relu(agg@W1 + b1) @ W2)).
template <int K1>
__global__ __launch_bounds__(256) void k_layer1_fused(const float* __restrict__ agg,
                                                      const float* __restrict__ W1,
                                                      const float* __restrict__ b1,
                                                      const float* __restrict__ W2,
                                                      const float* __restrict__ dinv,
                                                      __half* __restrict__ h, int n) {
    __shared__ float smem[HIDC * XS_STRIDE];   // phase1: agg^T tile; phase2: relu^T tile
    __shared__ float ws[HIDC * HIDC];          // phase1: W1; phase2: W2
    int tid = threadIdx.x;
    int n0 = blockIdx.x * MTILE;

    for (int i = tid; i < K1 * HIDC; i += 256) ws[i] = W1[i];
    for (int i = tid; i < MTILE * K1; i += 256) {
        int r = i / K1, k = i - r * K1;
        smem[k * XS_STRIDE + r] = (n0 + r < n) ? agg[(size_t)(n0 + r) * K1 + k] : 0.f;
    }
    __syncthreads();

    int c0 = (tid & 15) * 4;
    int m0 = (tid >> 4) * 8;
    float acc[8][4];
#pragma unroll
    for (int j = 0; j < 8; ++j)
#pragma unroll
        for (int q = 0; q < 4; ++q) acc[j][q] = 0.f;

#pragma unroll 2
    for (int k = 0; k < K1; ++k) {
        float4 a0 = *reinterpret_cast<const float4*>(&smem[k * XS_STRIDE + m0]);
        float4 a1 = *reinterpret_cast<const float4*>(&smem[k * XS_STRIDE + m0 + 4]);
        float4 b  = *reinterpret_cast<const float4*>(&ws[k * HIDC + c0]);
        float av[8] = {a0.x, a0.y, a0.z, a0.w, a1.x, a1.y, a1.z, a1.w};
        float bv[4] = {b.x, b.y, b.z, b.w};
#pragma unroll
        for (int j = 0; j < 8; ++j)
#pragma unroll
            for (int q = 0; q < 4; ++q)
                acc[j][q] = fmaf(av[j], bv[q], acc[j][q]);
    }

    float4 bb = *reinterpret_cast<const float4*>(b1 + c0);
    float bv4[4] = {bb.x, bb.y, bb.z, bb.w};
#pragma unroll
    for (int j = 0; j < 8; ++j)
#pragma unroll
        for (int q = 0; q < 4; ++q)
            acc[j][q] = fmaxf(acc[j][q] + bv4[q], 0.f);

    __syncthreads();   // phase-1 reads done; smem/ws reusable

#pragma unroll
    for (int j = 0; j < 8; ++j)
#pragma unroll
        for (int q = 0; q < 4; ++q)
            smem[(c0 + q) * XS_STRIDE + (m0 + j)] = (n0 + m0 + j < n) ? acc[j][q] : 0.f;
    for (int i = tid; i < HIDC * HIDC; i += 256) ws[i] = W2[i];
    __syncthreads();

#pragma unroll
    for (int j = 0; j < 8; ++j)
#pragma unroll
        for (int q = 0; q < 4; ++q) acc[j][q] = 0.f;

#pragma unroll 2
    for (int k = 0; k < HIDC; ++k) {
        float4 a0 = *reinterpret_cast<const float4*>(&smem[k * XS_STRIDE + m0]);
        float4 a1 = *reinterpret_cast<const float4*>(&smem[k * XS_STRIDE + m0 + 4]);
        float4 b  = *reinterpret_cast<const float4*>(&ws[k * HIDC + c0]);
        float av[8] = {a0.x, a0.y, a0.z, a0.w, a1.x, a1.y, a1.z, a1.w};
        float bv[4] = {b.x, b.y, b.z, b.w};
#pragma unroll
        for (int j = 0; j < 8; ++j)
#pragma unroll
            for (int q = 0; q < 4; ++q)
                acc[j][q] = fmaf(av[j], bv[q], acc[j][q]);
    }

#pragma unroll
    for (int j = 0; j < 8; ++j) {
        int node = n0 + m0 + j;
        if (node < n) {
            float dv = dinv[node];
            union { struct { __half2 a, b; } h2; float2 f2; } u;
            u.h2.a = __floats2half2_rn(acc[j][0] * dv, acc[j][1] * dv);
            u.h2.b = __floats2half2_rn(acc[j][2] * dv, acc[j][3] * dv);
            *reinterpret_cast<float2*>(h + (size_t)node * HIDC + c0) = u.f2;
        }
    }
}

// Layer-2 gather + fused mean-pool accumulate. 512 threads = 8 waves x 4 nodes
// = 32 consecutive nodes/block. Row -> LDS per-graph segment sums (batch sorted,
// <=MAXSEG segments per window; global-atomic fallback keeps it general).
__global__ __launch_bounds__(512) void k_gather_pool(const __half* __restrict__ h,
                                                     const int* __restrict__ off,
                                                     const u64* __restrict__ csr,
                                                     const float* __restrict__ dinv,
                                                     const float* __restrict__ bias,
                                                     const int* __restrict__ batch,
                                                     float* __restrict__ pooled,
                                                     float* __restrict__ cnt, int n) {
    __shared__ float segsum[MAXSEG][HIDC];
    __shared__ int segcnt[MAXSEG];
    __shared__ int sbase;
    int tid = threadIdx.x;
    int lane = tid & 63;
    int nodeInBlk = ((tid >> 6) << 2) + (lane >> 4);   // 0..31
    int node = blockIdx.x * 32 + nodeInBlk;
    int sub = lane & 15;                               // uint2 index (4 channels)
    if (tid < MAXSEG * HIDC) segsum[tid >> 6][tid & 63] = 0.f;
    if (tid < MAXSEG) segcnt[tid] = 0;
    if (tid == 0) {
        int i0 = (int)blockIdx.x * 32;
        if (i0 > n - 1) i0 = n - 1;
        sbase = batch[i0];
    }
    __syncthreads();

    if (node < n) {
        const uint2* hp = reinterpret_cast<const uint2*>(h);
        float d = dinv[node];
        uint2 sv = hp[(size_t)node * 16 + sub];
        float acc0, acc1, acc2, acc3;
        {
            float2 a = __half22float2(*(const __half2*)&sv.x);
            float2 b = __half22float2(*(const __half2*)&sv.y);
            acc0 = a.x; acc1 = a.y; acc2 = b.x; acc3 = b.y;
        }
        int i = off[node], e1 = off[node + 1];
        for (; i + 7 < e1; i += 8) {
            u64 e[8]; uint2 r[8];
#pragma unroll
            for (int j = 0; j < 8; ++j) e[j] = csr[i + j];
#pragma unroll
            for (int j = 0; j < 8; ++j) r[j] = hp[(size_t)(e[j] >> 32) * 16 + sub];
#pragma unroll
            for (int j = 0; j < 8; ++j) {
                float w = __uint_as_float((unsigned)e[j]);
                float2 a = __half22float2(*(const __half2*)&r[j].x);
                float2 b = __half22float2(*(const __half2*)&r[j].y);
                acc0 = fmaf(w, a.x, acc0); acc1 = fmaf(w, a.y, acc1);
                acc2 = fmaf(w, b.x, acc2); acc3 = fmaf(w, b.y, acc3);
            }
        }
        for (; i < e1; ++i) {
            u64 e0 = csr[i];
            uint2 r = hp[(size_t)(e0 >> 32) * 16 + sub];
            float w = __uint_as_float((unsigned)e0);
            float2 a = __half22float2(*(const __half2*)&r.x);
            float2 b = __half22float2(*(const __half2*)&r.y);
            acc0 = fmaf(w, a.x, acc0); acc1 = fmaf(w, a.y, acc1);
            acc2 = fmaf(w, b.x, acc2); acc3 = fmaf(w, b.y, acc3);
        }
        int c0 = sub * 4;
        float4 bb = *reinterpret_cast<const float4*>(bias + c0);
        float o0 = fmaxf(fmaf(d, acc0, bb.x), 0.f);
        float o1 = fmaxf(fmaf(d, acc1, bb.y), 0.f);
        float o2 = fmaxf(fmaf(d, acc2, bb.z), 0.f);
        float o3 = fmaxf(fmaf(d, acc3, bb.w), 0.f);
        int g = batch[node];
        int bl = g - sbase;
        if (bl >= 0 && bl < MAXSEG) {
            atomicAdd(&segsum[bl][c0 + 0], o0);
            atomicAdd(&segsum[bl][c0 + 1], o1);
            atomicAdd(&segsum[bl][c0 + 2], o2);
            atomicAdd(&segsum[bl][c0 + 3], o3);
            if (sub == 0) atomicAdd(&segcnt[bl], 1);
        } else {   // general fallback (never hit for realistic graph sizes)
            atomicAdd(&pooled[(size_t)g * HIDC + c0 + 0], o0);
            atomicAdd(&pooled[(size_t)g * HIDC + c0 + 1], o1);
            atomicAdd(&pooled[(size_t)g * HIDC + c0 + 2], o2);
            atomicAdd(&pooled[(size_t)g * HIDC + c0 + 3], o3);
            if (sub == 0) atomicAdd(&cnt[g], 1.f);
        }
    }
    __syncthreads();
    if (tid < MAXSEG * HIDC) {
        int sgi = tid >> 6, c = tid & 63;
        if (segcnt[sgi] > 0) {
            atomicAdd(&pooled[(size_t)(sbase + sgi) * HIDC + c], segsum[sgi][c]);
            if (c == 0) atomicAdd(&cnt[sbase + sgi], (float)segcnt[sgi]);
        }
    }
}

// One 64-thread block per graph: mean, fc1+relu, fc2.
__global__ void k_head(const float* __restrict__ pooled, const float* __restrict__ cnt,
                       const float* __restrict__ fw1, const float* __restrict__ fb1,
                       const float* __restrict__ fw2, const float* __restrict__ fb2,
                       float* __restrict__ out, int nclass) {
    int g = blockIdx.x;
    int j = threadIdx.x;
    __shared__ float p[HIDC], hid[HIDC];
    float c = fmaxf(cnt[g], 1.0f);
    p[j] = pooled[g * HIDC + j] / c;
    __syncthreads();
    float acc = fb1[j];
#pragma unroll 8
    for (int k = 0; k < HIDC; ++k) acc = fmaf(p[k], fw1[k * HIDC + j], acc);
    hid[j] = fmaxf(acc, 0.f);
    __syncthreads();
    if (j < nclass) {
        float o = fb2[j];
#pragma unroll 8
        for (int k = 0; k < HIDC; ++k) o = fmaf(hid[k], fw2[k * nclass + j], o);
        out[g * nclass + j] = o;
    }
}

extern "C" void kernel_launch(void* const* d_in, const int* in_sizes, int n_in,
                              void* d_out, int out_size, void* d_ws, size_t ws_size,
                              hipStream_t stream) {
    const float* x    = (const float*)d_in[0];
    const int* eidx   = (const int*)d_in[1];
    const float* ew   = (const float*)d_in[2];
    const int* batch  = (const int*)d_in[3];
    const float* W1   = (const float*)d_in[4];
    const float* b1   = (const float*)d_in[5];
    const float* W2   = (const float*)d_in[6];
    const float* b2   = (const float*)d_in[7];
    const float* fw1  = (const float*)d_in[8];
    const float* fb1  = (const float*)d_in[9];
    const float* fw2  = (const float*)d_in[10];
    const float* fb2  = (const float*)d_in[11];
    float* out = (float*)d_out;

    const int N = in_sizes[3];
    const int E = in_sizes[1] / 2;
    const int INCH = in_sizes[0] / N;          // 22
    const int NCLASS = in_sizes[11];
    const int G = out_size / NCLASS;
    const int NB = (N + SPAN - 1) >> BSHIFT;   // 196 for N=100000 (<=256 req.)

    const int* row = eidx;
    const int* col = eidx + E;

    // ---- workspace layout (8B-aligned arrays first) ----
    char* wp = (char*)d_ws;
    u64*   bedges = (u64*)wp;    wp += sizeof(u64) * E;
    u64*   csr    = (u64*)wp;    wp += sizeof(u64) * E;
    float* dinv   = (float*)wp;  wp += sizeof(float) * N;
    __half* x16   = (__half*)wp; wp += sizeof(__half) * (size_t)N * 32;
    float* agg    = (float*)wp;  wp += sizeof(float) * (size_t)N * INCH;
    __half* hbuf  = (__half*)wp; wp += sizeof(__half) * (size_t)N * HIDC;
    float* pooled = (float*)wp;  wp += sizeof(float) * (size_t)G * HIDC;
    float* cnt    = (float*)wp;  wp += sizeof(float) * G;
    int*   off    = (int*)wp;    wp += sizeof(int) * (N + 1);
    int*   bucket_cnt  = (int*)wp; wp += sizeof(int) * NBKT_MAX;
    int*   bucket_base = (int*)wp; wp += sizeof(int) * (NBKT_MAX + 1);
    int*   cursor_g    = (int*)wp; wp += sizeof(int) * NBKT_MAX;

    const int BLK = 256;
    dim3 blk(BLK);
    int gTile   = (N + MTILE - 1) / MTILE;
    int gAggX   = (N + 31) / 32;   // 8 nodes/wave * 4 waves
    int gGP     = (N + 31) / 32;   // 32 nodes per 512-thread block
    int nInit   = max(NB, G * HIDC + G);

    // init (bucket counts + pooled/cnt zeros)
    k_init<<<(nInit + BLK - 1) / BLK, blk, 0, stream>>>(bucket_cnt, NB, pooled, G * HIDC + G);

    // CSR build via bucket partition (+ fused x16 prep)
    k_bin_count<<<(E + 8191) / 8192, blk, 0, stream>>>(col, bucket_cnt, E, NB);
    k_bucket_scan<<<1, blk, 0, stream>>>(bucket_cnt, bucket_base, cursor_g, NB, E);
    k_bin_scatter<<<(E + BCHUNK - 1) / BCHUNK, blk, 0, stream>>>(row, col, ew, cursor_g,
                                                                 bedges, E, NB);
    k_bucket_process<<<NB, blk, 0, stream>>>(bedges, bucket_base, x, csr, dinv, off, x16,
                                             N, E, NB, INCH);

    // layer 1: agg = dinv*(x16self + sum w*x16src); hbuf = fp16(dinv*(relu(agg@W1+b1)@W2))
    k_agg_x<<<gAggX, blk, 0, stream>>>(x16, off, csr, dinv, agg, N, INCH);
    k_layer1_fused<22><<<gTile, blk, 0, stream>>>(agg, W1, b1, W2, dinv, hbuf, N);

    // layer 2 gather + pool fused
    k_gather_pool<<<gGP, dim3(512), 0, stream>>>(hbuf, off, csr, dinv, b2, batch,
                                                 pooled, cnt, N);

    // head
    k_head<<<G, dim3(64), 0, stream>>>(pooled, cnt, fw1, fb1, fw2, fb2, out, NCLASS);
}

// Round 12
// 201.554 us; speedup vs baseline: 1.0415x; 1.0415x over previous
//
#include <hip/hip_runtime.h>
#include <hip/hip_bf16.h>
#include <hip/hip_fp16.h>

// GCN forward: 2x GCNConv(relu) -> global_mean_pool -> MLP head.
// Round 12: revert the gather+pool fusion (barrier tail + occupancy loss cost
//          30us to save 16us). Keep: x16-prep fused in bucket_process,
//          4-node/wave gathers, fused layer-1 GEMM pair. 9 launches.

#define HIDC 64
#define MTILE 128
#define XS_STRIDE (MTILE + 4)
#define BSHIFT 9
#define SPAN 512          // nodes per bucket
#define NBKT_MAX 256      // requires N <= 131072
#define BCHUNK 2048       // edges per workgroup in k_bin_scatter

typedef unsigned long long u64;

// zero bucket_cnt (NB ints) + pooled/cnt (G*65 floats, contiguous)
__global__ void k_init(int* bucket_cnt, int nb, float* pooled, int npool) {
    int i = blockIdx.x * blockDim.x + threadIdx.x;
    if (i < nb) bucket_cnt[i] = 0;
    if (i < npool) pooled[i] = 0.f;
}

// per-workgroup LDS histogram of edge destinations by bucket
__global__ __launch_bounds__(256) void k_bin_count(const int* __restrict__ col,
                                                   int* bucket_cnt, int E, int NB) {
    __shared__ int hist[NBKT_MAX];
    int tid = threadIdx.x;
    for (int i = tid; i < NB; i += 256) hist[i] = 0;
    __syncthreads();
    int base = blockIdx.x * 8192;
    for (int j = 0; j < 32; ++j) {
        int e = base + j * 256 + tid;
        if (e < E) atomicAdd(&hist[col[e] >> BSHIFT], 1);
    }
    __syncthreads();
    for (int i = tid; i < NB; i += 256)
        if (hist[i]) atomicAdd(&bucket_cnt[i], hist[i]);
}

// exclusive scan of bucket counts (NB <= 256); emits base + cursor copy
__global__ void k_bucket_scan(const int* __restrict__ bucket_cnt, int* __restrict__ bucket_base,
                              int* __restrict__ cursor_g, int NB, int E) {
    __shared__ int s[256];
    int t = threadIdx.x;
    int v = (t < NB) ? bucket_cnt[t] : 0;
    s[t] = v;
    __syncthreads();
    for (int o = 1; o < 256; o <<= 1) {
        int x = (t >= o) ? s[t - o] : 0;
        __syncthreads();
        s[t] += x;
        __syncthreads();
    }
    if (t < NB) { int ex = s[t] - v; bucket_base[t] = ex; cursor_g[t] = ex; }
    if (t == 0) bucket_base[NB] = E;
}

// partition edges into destination buckets via LDS staging; flushes are
// contiguous runs per bucket (coalesced). packed = ew(32) | src(23) | colin(9).
__global__ __launch_bounds__(256) void k_bin_scatter(const int* __restrict__ row,
                                                     const int* __restrict__ col,
                                                     const float* __restrict__ ew,
                                                     int* cursor_g, u64* __restrict__ bedges,
                                                     int E, int NB) {
    __shared__ int hist[NBKT_MAX], binoff[NBKT_MAX], cursor[NBKT_MAX], gbase[NBKT_MAX];
    __shared__ int s[256];
    __shared__ u64 stage[BCHUNK];
    __shared__ unsigned char binid[BCHUNK];
    int tid = threadIdx.x;
    for (int i = tid; i < NB; i += 256) hist[i] = 0;
    __syncthreads();
    int base = blockIdx.x * BCHUNK;
    u64 pk[8]; int bb[8];
#pragma unroll
    for (int j = 0; j < 8; ++j) {
        int e = base + j * 256 + tid;
        if (e < E) {
            int c = col[e];
            bb[j] = c >> BSHIFT;
            pk[j] = ((u64)__float_as_uint(ew[e]) << 32) |
                    ((u64)(unsigned)row[e] << BSHIFT) | (unsigned)(c & (SPAN - 1));
            atomicAdd(&hist[bb[j]], 1);
        } else bb[j] = -1;
    }
    __syncthreads();
    {   // exclusive scan of hist -> binoff
        int v = (tid < NB) ? hist[tid] : 0;
        s[tid] = v;
        __syncthreads();
        for (int o = 1; o < 256; o <<= 1) {
            int x = (tid >= o) ? s[tid - o] : 0;
            __syncthreads();
            s[tid] += x;
            __syncthreads();
        }
        if (tid < NB) { binoff[tid] = s[tid] - v; cursor[tid] = s[tid] - v; }
    }
    __syncthreads();
#pragma unroll
    for (int j = 0; j < 8; ++j)
        if (bb[j] >= 0) {
            int pos = atomicAdd(&cursor[bb[j]], 1);
            stage[pos] = pk[j];
            binid[pos] = (unsigned char)bb[j];
        }
    __syncthreads();
    if (tid < NB && hist[tid] > 0) gbase[tid] = atomicAdd(&cursor_g[tid], hist[tid]);
    __syncthreads();
    int total = min(BCHUNK, E - base);
    for (int i = tid; i < total; i += 256) {
        int b = binid[i];
        bedges[(size_t)gbase[b] + (i - binoff[b])] = stage[i];
    }
}

// one workgroup per bucket: LDS degree accumulate, scan -> CSR offsets,
// in-bucket scatter, emit dinv + off + scaled fp16 x-rows (prep fused).
__global__ __launch_bounds__(256) void k_bucket_process(const u64* __restrict__ bedges,
                                                        const int* __restrict__ bucket_base,
                                                        const float* __restrict__ x,
                                                        u64* __restrict__ csr,
                                                        float* __restrict__ dinv,
                                                        int* __restrict__ off,
                                                        __half* __restrict__ x16,
                                                        int N, int E, int NB, int K) {
    __shared__ float deg[SPAN];
    __shared__ int cL[SPAN];
    __shared__ int offL[SPAN];
    __shared__ int s[256];
    int b = blockIdx.x, tid = threadIdx.x;
    int ebase = bucket_base[b], ecnt = bucket_base[b + 1] - ebase;
    int nd0 = b << BSHIFT;
    int ndn = min(SPAN, N - nd0);
    for (int i = tid; i < SPAN; i += 256) { deg[i] = 1.0f; cL[i] = 0; }
    __syncthreads();
    for (int e = tid; e < ecnt; e += 256) {
        u64 p = bedges[ebase + e];
        int colin = (int)(p & (SPAN - 1));
        atomicAdd(&deg[colin], __uint_as_float((unsigned)(p >> 32)));
        atomicAdd(&cL[colin], 1);
    }
    __syncthreads();
    // exclusive scan of cL[0..SPAN) via pairs (SPAN = 2*256)
    int p0 = cL[2 * tid], p1 = cL[2 * tid + 1];
    s[tid] = p0 + p1;
    __syncthreads();
    for (int o = 1; o < 256; o <<= 1) {
        int x_ = (tid >= o) ? s[tid - o] : 0;
        __syncthreads();
        s[tid] += x_;
        __syncthreads();
    }
    int ex = s[tid] - (p0 + p1);
    offL[2 * tid] = ex;
    offL[2 * tid + 1] = ex + p0;
    __syncthreads();
    for (int i = tid; i < ndn; i += 256) {
        float dv = rsqrtf(deg[i]);
        deg[i] = dv;                       // keep dinv in LDS for the x16 pass
        dinv[nd0 + i] = dv;
        off[nd0 + i] = ebase + offL[i];
    }
    for (int i = tid; i < SPAN; i += 256) cL[i] = offL[i];   // cursors
    if (b == NB - 1 && tid == 0) off[N] = E;
    __syncthreads();
    // CSR scatter within bucket (L2-resident region)
    for (int e = tid; e < ecnt; e += 256) {
        u64 p = bedges[ebase + e];
        int colin = (int)(p & (SPAN - 1));
        int src = (int)((p >> BSHIFT) & 0x7FFFFF);   // 23 bits
        int slot = atomicAdd(&cL[colin], 1);
        csr[(size_t)ebase + slot] = ((u64)(unsigned)src << 32) | (unsigned)(p >> 32);
    }
    // fused prep: x16[node][32] = fp16(dinv*x[node][0..K)), rest zero (64B rows)
    for (int i = tid; i < ndn * 16; i += 256) {
        int nl = i >> 4, p = i & 15, c0 = p * 2;
        float dv = deg[nl];
        const float* xr = x + (size_t)(nd0 + nl) * K;
        float a = (c0 < K)     ? dv * xr[c0]     : 0.f;
        float bq = (c0 + 1 < K) ? dv * xr[c0 + 1] : 0.f;
        reinterpret_cast<__half2*>(x16)[(size_t)(nd0 + nl) * 16 + p] = __floats2half2_rn(a, bq);
    }
}

// Layer-1 aggregation over raw x: 8 nodes/wave (8 lanes each, uint2 = 4ch/lane),
// 8-wide edge unroll -> up to 64 row fetches in flight per wave.
__global__ void k_agg_x(const __half* __restrict__ x16, const int* __restrict__ off,
                        const u64* __restrict__ csr, const float* __restrict__ dinv,
                        float* __restrict__ agg, int n, int K) {
    int t = blockIdx.x * blockDim.x + threadIdx.x;
    int lane = threadIdx.x & 63;
    int node = ((t >> 6) << 3) + (lane >> 3);   // 8 nodes per wave
    int sub = lane & 7;                         // uint2 index (4 channels)
    if (node >= n) return;
    const uint2* xp = reinterpret_cast<const uint2*>(x16);   // 8 uint2 per row
    uint2 sv = xp[(size_t)node * 8 + sub];
    float acc0, acc1, acc2, acc3;
    {
        float2 a = __half22float2(*(const __half2*)&sv.x);
        float2 b = __half22float2(*(const __half2*)&sv.y);
        acc0 = a.x; acc1 = a.y; acc2 = b.x; acc3 = b.y;
    }
    int i = off[node], e1 = off[node + 1];
    for (; i + 7 < e1; i += 8) {
        u64 e[8]; uint2 r[8];
#pragma unroll
        for (int j = 0; j < 8; ++j) e[j] = csr[i + j];
#pragma unroll
        for (int j = 0; j < 8; ++j) r[j] = xp[(size_t)(e[j] >> 32) * 8 + sub];
#pragma unroll
        for (int j = 0; j < 8; ++j) {
            float w = __uint_as_float((unsigned)e[j]);
            float2 a = __half22float2(*(const __half2*)&r[j].x);
            float2 b = __half22float2(*(const __half2*)&r[j].y);
            acc0 = fmaf(w, a.x, acc0); acc1 = fmaf(w, a.y, acc1);
            acc2 = fmaf(w, b.x, acc2); acc3 = fmaf(w, b.y, acc3);
        }
    }
    for (; i < e1; ++i) {
        u64 e0 = csr[i];
        uint2 r = xp[(size_t)(e0 >> 32) * 8 + sub];
        float w = __uint_as_float((unsigned)e0);
        float2 a = __half22float2(*(const __half2*)&r.x);
        float2 b = __half22float2(*(const __half2*)&r.y);
        acc0 = fmaf(w, a.x, acc0); acc1 = fmaf(w, a.y, acc1);
        acc2 = fmaf(w, b.x, acc2); acc3 = fmaf(w, b.y, acc3);
    }
    int c0 = sub * 4;
    float d = dinv[node];
    float* ap = agg + (size_t)node * K + c0;
    if (c0 + 3 < K) {
        float2 o0; o0.x = d * acc0; o0.y = d * acc1;
        float2 o1; o1.x = d * acc2; o1.y = d * acc3;
        *reinterpret_cast<float2*>(ap) = o0;
        *reinterpret_cast<float2*>(ap + 2) = o1;
    } else if (c0 < K) {   // K=22: c0==20 -> last 2 channels
        float2 o; o.x = d * acc0; o.y = d * acc1;
        *reinterpret_cast<float2*>(ap) = o;
    }
}

// Fused layer-1 transform: hbuf = fp16(dinv * (relu(agg@W1 + b1) @ W2)).
template <int K1>
__global__ __launch_bounds__(256) void k_layer1_fused(const float* __restrict__ agg,
                                                      const float* __restrict__ W1,
                                                      const float* __restrict__ b1,
                                                      const float* __restrict__ W2,
                                                      const float* __restrict__ dinv,
                                                      __half* __restrict__ h, int n) {
    __shared__ float smem[HIDC * XS_STRIDE];   // phase1: agg^T tile; phase2: relu^T tile
    __shared__ float ws[HIDC * HIDC];          // phase1: W1; phase2: W2
    int tid = threadIdx.x;
    int n0 = blockIdx.x * MTILE;

    for (int i = tid; i < K1 * HIDC; i += 256) ws[i] = W1[i];
    for (int i = tid; i < MTILE * K1; i += 256) {
        int r = i / K1, k = i - r * K1;
        smem[k * XS_STRIDE + r] = (n0 + r < n) ? agg[(size_t)(n0 + r) * K1 + k] : 0.f;
    }
    __syncthreads();

    int c0 = (tid & 15) * 4;
    int m0 = (tid >> 4) * 8;
    float acc[8][4];
#pragma unroll
    for (int j = 0; j < 8; ++j)
#pragma unroll
        for (int q = 0; q < 4; ++q) acc[j][q] = 0.f;

#pragma unroll 2
    for (int k = 0; k < K1; ++k) {
        float4 a0 = *reinterpret_cast<const float4*>(&smem[k * XS_STRIDE + m0]);
        float4 a1 = *reinterpret_cast<const float4*>(&smem[k * XS_STRIDE + m0 + 4]);
        float4 b  = *reinterpret_cast<const float4*>(&ws[k * HIDC + c0]);
        float av[8] = {a0.x, a0.y, a0.z, a0.w, a1.x, a1.y, a1.z, a1.w};
        float bv[4] = {b.x, b.y, b.z, b.w};
#pragma unroll
        for (int j = 0; j < 8; ++j)
#pragma unroll
            for (int q = 0; q < 4; ++q)
                acc[j][q] = fmaf(av[j], bv[q], acc[j][q]);
    }

    float4 bb = *reinterpret_cast<const float4*>(b1 + c0);
    float bv4[4] = {bb.x, bb.y, bb.z, bb.w};
#pragma unroll
    for (int j = 0; j < 8; ++j)
#pragma unroll
        for (int q = 0; q < 4; ++q)
            acc[j][q] = fmaxf(acc[j][q] + bv4[q], 0.f);

    __syncthreads();   // phase-1 reads done; smem/ws reusable

#pragma unroll
    for (int j = 0; j < 8; ++j)
#pragma unroll
        for (int q = 0; q < 4; ++q)
            smem[(c0 + q) * XS_STRIDE + (m0 + j)] = (n0 + m0 + j < n) ? acc[j][q] : 0.f;
    for (int i = tid; i < HIDC * HIDC; i += 256) ws[i] = W2[i];
    __syncthreads();

#pragma unroll
    for (int j = 0; j < 8; ++j)
#pragma unroll
        for (int q = 0; q < 4; ++q) acc[j][q] = 0.f;

#pragma unroll 2
    for (int k = 0; k < HIDC; ++k) {
        float4 a0 = *reinterpret_cast<const float4*>(&smem[k * XS_STRIDE + m0]);
        float4 a1 = *reinterpret_cast<const float4*>(&smem[k * XS_STRIDE + m0 + 4]);
        float4 b  = *reinterpret_cast<const float4*>(&ws[k * HIDC + c0]);
        float av[8] = {a0.x, a0.y, a0.z, a0.w, a1.x, a1.y, a1.z, a1.w};
        float bv[4] = {b.x, b.y, b.z, b.w};
#pragma unroll
        for (int j = 0; j < 8; ++j)
#pragma unroll
            for (int q = 0; q < 4; ++q)
                acc[j][q] = fmaf(av[j], bv[q], acc[j][q]);
    }

#pragma unroll
    for (int j = 0; j < 8; ++j) {
        int node = n0 + m0 + j;
        if (node < n) {
            float dv = dinv[node];
            union { struct { __half2 a, b; } h2; float2 f2; } u;
            u.h2.a = __floats2half2_rn(acc[j][0] * dv, acc[j][1] * dv);
            u.h2.b = __floats2half2_rn(acc[j][2] * dv, acc[j][3] * dv);
            *reinterpret_cast<float2*>(h + (size_t)node * HIDC + c0) = u.f2;
        }
    }
}

// Layer-2 gather: 4 nodes/wave (16 lanes x uint2 = 4ch), 8-wide edge unroll
// -> 32 row fetches in flight. out = relu(dinv*(h'self + sum w*h'src) + b).
__global__ void k_gcn_gather(const __half* __restrict__ h, const int* __restrict__ off,
                             const u64* __restrict__ csr, const float* __restrict__ dinv,
                             const float* __restrict__ bias, float* __restrict__ out, int n) {
    int t = blockIdx.x * blockDim.x + threadIdx.x;
    int lane = threadIdx.x & 63;
    int node = ((t >> 6) << 2) + (lane >> 4);   // 4 nodes per wave
    int sub = lane & 15;                        // uint2 index (4 channels)
    if (node >= n) return;
    const uint2* hp = reinterpret_cast<const uint2*>(h);   // 16 uint2 per row
    float d = dinv[node];
    uint2 sv = hp[(size_t)node * 16 + sub];
    float acc0, acc1, acc2, acc3;
    {
        float2 a = __half22float2(*(const __half2*)&sv.x);
        float2 b = __half22float2(*(const __half2*)&sv.y);
        acc0 = a.x; acc1 = a.y; acc2 = b.x; acc3 = b.y;
    }
    int i = off[node], e1 = off[node + 1];
    for (; i + 7 < e1; i += 8) {
        u64 e[8]; uint2 r[8];
#pragma unroll
        for (int j = 0; j < 8; ++j) e[j] = csr[i + j];
#pragma unroll
        for (int j = 0; j < 8; ++j) r[j] = hp[(size_t)(e[j] >> 32) * 16 + sub];
#pragma unroll
        for (int j = 0; j < 8; ++j) {
            float w = __uint_as_float((unsigned)e[j]);
            float2 a = __half22float2(*(const __half2*)&r[j].x);
            float2 b = __half22float2(*(const __half2*)&r[j].y);
            acc0 = fmaf(w, a.x, acc0); acc1 = fmaf(w, a.y, acc1);
            acc2 = fmaf(w, b.x, acc2); acc3 = fmaf(w, b.y, acc3);
        }
    }
    for (; i < e1; ++i) {
        u64 e0 = csr[i];
        uint2 r = hp[(size_t)(e0 >> 32) * 16 + sub];
        float w = __uint_as_float((unsigned)e0);
        float2 a = __half22float2(*(const __half2*)&r.x);
        float2 b = __half22float2(*(const __half2*)&r.y);
        acc0 = fmaf(w, a.x, acc0); acc1 = fmaf(w, a.y, acc1);
        acc2 = fmaf(w, b.x, acc2); acc3 = fmaf(w, b.y, acc3);
    }
    int c0 = sub * 4;
    float4 bb = *reinterpret_cast<const float4*>(bias + c0);
    float4 o;
    o.x = fmaxf(fmaf(d, acc0, bb.x), 0.f);
    o.y = fmaxf(fmaf(d, acc1, bb.y), 0.f);
    o.z = fmaxf(fmaf(d, acc2, bb.z), 0.f);
    o.w = fmaxf(fmaf(d, acc3, bb.w), 0.f);
    *reinterpret_cast<float4*>(out + (size_t)node * HIDC + c0) = o;
}

// batch is sorted: segmented accumulate, flush (atomic) only on graph change.
__global__ void k_pool(const float* __restrict__ h, const int* __restrict__ batch,
                       float* __restrict__ pooled, float* __restrict__ cnt, int n) {
    int c = threadIdx.x & 63, sub = threadIdx.x >> 6;
    int n0 = blockIdx.x * 256;
    int nend = min(n0 + 256, n);
    float acc = 0.f, cacc = 0.f;
    int curb = -1;
    for (int i = n0 + sub; i < nend; i += 4) {
        int b = batch[i];
        if (b != curb) {
            if (curb >= 0) {
                atomicAdd(&pooled[curb * HIDC + c], acc);
                if (c == 0) atomicAdd(&cnt[curb], cacc);
            }
            acc = 0.f; cacc = 0.f;
            curb = b;
        }
        acc += h[(size_t)i * HIDC + c];
        cacc += 1.f;
    }
    if (curb >= 0) {
        atomicAdd(&pooled[curb * HIDC + c], acc);
        if (c == 0) atomicAdd(&cnt[curb], cacc);
    }
}

// One 64-thread block per graph: mean, fc1+relu, fc2.
__global__ void k_head(const float* __restrict__ pooled, const float* __restrict__ cnt,
                       const float* __restrict__ fw1, const float* __restrict__ fb1,
                       const float* __restrict__ fw2, const float* __restrict__ fb2,
                       float* __restrict__ out, int nclass) {
    int g = blockIdx.x;
    int j = threadIdx.x;
    __shared__ float p[HIDC], hid[HIDC];
    float c = fmaxf(cnt[g], 1.0f);
    p[j] = pooled[g * HIDC + j] / c;
    __syncthreads();
    float acc = fb1[j];
#pragma unroll 8
    for (int k = 0; k < HIDC; ++k) acc = fmaf(p[k], fw1[k * HIDC + j], acc);
    hid[j] = fmaxf(acc, 0.f);
    __syncthreads();
    if (j < nclass) {
        float o = fb2[j];
#pragma unroll 8
        for (int k = 0; k < HIDC; ++k) o = fmaf(hid[k], fw2[k * nclass + j], o);
        out[g * nclass + j] = o;
    }
}

extern "C" void kernel_launch(void* const* d_in, const int* in_sizes, int n_in,
                              void* d_out, int out_size, void* d_ws, size_t ws_size,
                              hipStream_t stream) {
    const float* x    = (const float*)d_in[0];
    const int* eidx   = (const int*)d_in[1];
    const float* ew   = (const float*)d_in[2];
    const int* batch  = (const int*)d_in[3];
    const float* W1   = (const float*)d_in[4];
    const float* b1   = (const float*)d_in[5];
    const float* W2   = (const float*)d_in[6];
    const float* b2   = (const float*)d_in[7];
    const float* fw1  = (const float*)d_in[8];
    const float* fb1  = (const float*)d_in[9];
    const float* fw2  = (const float*)d_in[10];
    const float* fb2  = (const float*)d_in[11];
    float* out = (float*)d_out;

    const int N = in_sizes[3];
    const int E = in_sizes[1] / 2;
    const int INCH = in_sizes[0] / N;          // 22
    const int NCLASS = in_sizes[11];
    const int G = out_size / NCLASS;
    const int NB = (N + SPAN - 1) >> BSHIFT;   // 196 for N=100000 (<=256 req.)

    const int* row = eidx;
    const int* col = eidx + E;

    // ---- workspace layout (8B-aligned arrays first) ----
    char* wp = (char*)d_ws;
    u64*   bedges = (u64*)wp;    wp += sizeof(u64) * E;
    u64*   csr    = (u64*)wp;    wp += sizeof(u64) * E;
    float* dinv   = (float*)wp;  wp += sizeof(float) * N;
    __half* x16   = (__half*)wp; wp += sizeof(__half) * (size_t)N * 32;
    float* agg    = (float*)wp;  wp += sizeof(float) * (size_t)N * INCH;
    __half* hbuf  = (__half*)wp; wp += sizeof(__half) * (size_t)N * HIDC;
    float* bufB   = (float*)wp;  wp += sizeof(float) * (size_t)N * HIDC;
    float* pooled = (float*)wp;  wp += sizeof(float) * (size_t)G * HIDC;
    float* cnt    = (float*)wp;  wp += sizeof(float) * G;
    int*   off    = (int*)wp;    wp += sizeof(int) * (N + 1);
    int*   bucket_cnt  = (int*)wp; wp += sizeof(int) * NBKT_MAX;
    int*   bucket_base = (int*)wp; wp += sizeof(int) * (NBKT_MAX + 1);
    int*   cursor_g    = (int*)wp; wp += sizeof(int) * NBKT_MAX;

    const int BLK = 256;
    dim3 blk(BLK);
    int gTile   = (N + MTILE - 1) / MTILE;
    int gAggX   = (N + 31) / 32;   // 8 nodes/wave * 4 waves
    int gGather = (N + 15) / 16;   // 4 nodes/wave * 4 waves
    int nInit   = max(NB, G * HIDC + G);

    // init (bucket counts + pooled/cnt zeros)
    k_init<<<(nInit + BLK - 1) / BLK, blk, 0, stream>>>(bucket_cnt, NB, pooled, G * HIDC + G);

    // CSR build via bucket partition (+ fused x16 prep)
    k_bin_count<<<(E + 8191) / 8192, blk, 0, stream>>>(col, bucket_cnt, E, NB);
    k_bucket_scan<<<1, blk, 0, stream>>>(bucket_cnt, bucket_base, cursor_g, NB, E);
    k_bin_scatter<<<(E + BCHUNK - 1) / BCHUNK, blk, 0, stream>>>(row, col, ew, cursor_g,
                                                                 bedges, E, NB);
    k_bucket_process<<<NB, blk, 0, stream>>>(bedges, bucket_base, x, csr, dinv, off, x16,
                                             N, E, NB, INCH);

    // layer 1: agg = dinv*(x16self + sum w*x16src); hbuf = fp16(dinv*(relu(agg@W1+b1)@W2))
    k_agg_x<<<gAggX, blk, 0, stream>>>(x16, off, csr, dinv, agg, N, INCH);
    k_layer1_fused<22><<<gTile, blk, 0, stream>>>(agg, W1, b1, W2, dinv, hbuf, N);

    // layer 2 gather -> bufB
    k_gcn_gather<<<gGather, blk, 0, stream>>>(hbuf, off, csr, dinv, b2, bufB, N);

    // pool + head
    k_pool<<<(N + 255) / 256, blk, 0, stream>>>(bufB, batch, pooled, cnt, N);
    k_head<<<G, dim3(64), 0, stream>>>(pooled, cnt, fw1, fb1, fw2, fb2, out, NCLASS);
}

// Round 13
// 193.887 us; speedup vs baseline: 1.0827x; 1.0395x over previous
//
#include <hip/hip_runtime.h>
#include <hip/hip_bf16.h>
#include <hip/hip_fp16.h>

// GCN forward: 2x GCNConv(relu) -> global_mean_pool -> MLP head.
// Round 13: bucket stage parallelized — SPAN 512->256 (391 blocks, was 196),
//           deg+count packed into ONE u64 LDS atomic per edge.

#define HIDC 64
#define MTILE 128
#define XS_STRIDE (MTILE + 4)
#define BSHIFT 8
#define SPAN 256          // nodes per bucket
#define NBKT_MAX 512      // requires N <= 131072
#define BCHUNK 2048       // edges per workgroup in k_bin_scatter
#define SUM_MASK ((1ULL << 48) - 1)

typedef unsigned long long u64;

// zero bucket_cnt (NB ints) + pooled/cnt (G*65 floats, contiguous)
__global__ void k_init(int* bucket_cnt, int nb, float* pooled, int npool) {
    int i = blockIdx.x * blockDim.x + threadIdx.x;
    if (i < nb) bucket_cnt[i] = 0;
    if (i < npool) pooled[i] = 0.f;
}

// per-workgroup LDS histogram of edge destinations by bucket
__global__ __launch_bounds__(256) void k_bin_count(const int* __restrict__ col,
                                                   int* bucket_cnt, int E, int NB) {
    __shared__ int hist[NBKT_MAX];
    int tid = threadIdx.x;
    for (int i = tid; i < NB; i += 256) hist[i] = 0;
    __syncthreads();
    int base = blockIdx.x * 8192;
    for (int j = 0; j < 32; ++j) {
        int e = base + j * 256 + tid;
        if (e < E) atomicAdd(&hist[col[e] >> BSHIFT], 1);
    }
    __syncthreads();
    for (int i = tid; i < NB; i += 256)
        if (hist[i]) atomicAdd(&bucket_cnt[i], hist[i]);
}

// exclusive scan of bucket counts (NB <= 512, 2 elems/thread)
__global__ void k_bucket_scan(const int* __restrict__ bucket_cnt, int* __restrict__ bucket_base,
                              int* __restrict__ cursor_g, int NB, int E) {
    __shared__ int s[256];
    int t = threadIdx.x;
    int i0 = 2 * t, i1 = 2 * t + 1;
    int v0 = (i0 < NB) ? bucket_cnt[i0] : 0;
    int v1 = (i1 < NB) ? bucket_cnt[i1] : 0;
    s[t] = v0 + v1;
    __syncthreads();
    for (int o = 1; o < 256; o <<= 1) {
        int x = (t >= o) ? s[t - o] : 0;
        __syncthreads();
        s[t] += x;
        __syncthreads();
    }
    int ex = s[t] - (v0 + v1);
    if (i0 < NB) { bucket_base[i0] = ex;      cursor_g[i0] = ex; }
    if (i1 < NB) { bucket_base[i1] = ex + v0; cursor_g[i1] = ex + v0; }
    if (t == 0) bucket_base[NB] = E;
}

// partition edges into destination buckets via LDS staging; flushes are
// contiguous runs per bucket (coalesced). packed = ew(32) | src(23) | colin(8).
__global__ __launch_bounds__(256) void k_bin_scatter(const int* __restrict__ row,
                                                     const int* __restrict__ col,
                                                     const float* __restrict__ ew,
                                                     int* cursor_g, u64* __restrict__ bedges,
                                                     int E, int NB) {
    __shared__ int hist[NBKT_MAX], binoff[NBKT_MAX], cursor[NBKT_MAX], gbase[NBKT_MAX];
    __shared__ int s[256];
    __shared__ u64 stage[BCHUNK];
    __shared__ unsigned short binid[BCHUNK];
    int tid = threadIdx.x;
    for (int i = tid; i < NB; i += 256) hist[i] = 0;
    __syncthreads();
    int base = blockIdx.x * BCHUNK;
    u64 pk[8]; int bb[8];
#pragma unroll
    for (int j = 0; j < 8; ++j) {
        int e = base + j * 256 + tid;
        if (e < E) {
            int c = col[e];
            bb[j] = c >> BSHIFT;
            pk[j] = ((u64)__float_as_uint(ew[e]) << 32) |
                    ((u64)(unsigned)row[e] << BSHIFT) | (unsigned)(c & (SPAN - 1));
            atomicAdd(&hist[bb[j]], 1);
        } else bb[j] = -1;
    }
    __syncthreads();
    {   // exclusive scan of hist[0..NB) -> binoff/cursor, 2 elems/thread
        int i0 = 2 * tid, i1 = 2 * tid + 1;
        int v0 = (i0 < NB) ? hist[i0] : 0;
        int v1 = (i1 < NB) ? hist[i1] : 0;
        s[tid] = v0 + v1;
        __syncthreads();
        for (int o = 1; o < 256; o <<= 1) {
            int x = (tid >= o) ? s[tid - o] : 0;
            __syncthreads();
            s[tid] += x;
            __syncthreads();
        }
        int ex = s[tid] - (v0 + v1);
        if (i0 < NB) { binoff[i0] = ex;      cursor[i0] = ex; }
        if (i1 < NB) { binoff[i1] = ex + v0; cursor[i1] = ex + v0; }
    }
    __syncthreads();
#pragma unroll
    for (int j = 0; j < 8; ++j)
        if (bb[j] >= 0) {
            int pos = atomicAdd(&cursor[bb[j]], 1);
            stage[pos] = pk[j];
            binid[pos] = (unsigned short)bb[j];
        }
    __syncthreads();
    for (int i = tid; i < NB; i += 256)
        if (hist[i] > 0) gbase[i] = atomicAdd(&cursor_g[i], hist[i]);
    __syncthreads();
    int total = min(BCHUNK, E - base);
    for (int i = tid; i < total; i += 256) {
        int b = binid[i];
        bedges[(size_t)gbase[b] + (i - binoff[b])] = stage[i];
    }
}

// one workgroup per bucket (SPAN=256): ONE packed u64 LDS atomic per edge for
// deg+count, scan -> CSR offsets, in-bucket scatter, dinv/off/x16 emit.
__global__ __launch_bounds__(256) void k_bucket_process(const u64* __restrict__ bedges,
                                                        const int* __restrict__ bucket_base,
                                                        const float* __restrict__ x,
                                                        u64* __restrict__ csr,
                                                        float* __restrict__ dinv,
                                                        int* __restrict__ off,
                                                        __half* __restrict__ x16,
                                                        int N, int E, int NB, int K) {
    __shared__ u64 degp[SPAN];      // Q16.32 weighted degree | count<<48
    __shared__ int cL[SPAN];
    __shared__ int offL[SPAN];
    __shared__ float dvL[SPAN];
    __shared__ int s[256];
    int b = blockIdx.x, tid = threadIdx.x;
    int ebase = bucket_base[b], ecnt = bucket_base[b + 1] - ebase;
    int nd0 = b << BSHIFT;
    int ndn = min(SPAN, N - nd0);
    degp[tid] = (1ULL << 32);   // self-loop weight 1.0, count 0
    __syncthreads();
    for (int e = tid; e < ecnt; e += 256) {
        u64 p = bedges[ebase + e];
        int colin = (int)(p & (SPAN - 1));
        float w = __uint_as_float((unsigned)(p >> 32));
        u64 add = (u64)((double)w * 4294967296.0 + 0.5) | (1ULL << 48);
        atomicAdd(&degp[colin], add);
    }
    __syncthreads();
    // exclusive scan of counts (1 elem/thread, SPAN==256)
    int cnt_t = (int)(degp[tid] >> 48);
    s[tid] = cnt_t;
    __syncthreads();
    for (int o = 1; o < 256; o <<= 1) {
        int x_ = (tid >= o) ? s[tid - o] : 0;
        __syncthreads();
        s[tid] += x_;
        __syncthreads();
    }
    int ex = s[tid] - cnt_t;
    offL[tid] = ex;
    cL[tid] = ex;
    float dv = rsqrtf((float)((double)(degp[tid] & SUM_MASK) * 2.3283064365386963e-10));
    dvL[tid] = dv;
    if (tid < ndn) {
        dinv[nd0 + tid] = dv;
        off[nd0 + tid] = ebase + ex;
    }
    if (b == NB - 1 && tid == 0) off[N] = E;
    __syncthreads();
    // CSR scatter within bucket (L2-resident region)
    for (int e = tid; e < ecnt; e += 256) {
        u64 p = bedges[ebase + e];
        int colin = (int)(p & (SPAN - 1));
        int src = (int)((p >> BSHIFT) & 0x7FFFFF);   // 23 bits
        int slot = atomicAdd(&cL[colin], 1);
        csr[(size_t)ebase + slot] = ((u64)(unsigned)src << 32) | (unsigned)(p >> 32);
    }
    // fused prep: x16[node][32] = fp16(dinv*x[node][0..K)), rest zero (64B rows)
    for (int i = tid; i < ndn * 16; i += 256) {
        int nl = i >> 4, p = i & 15, c0 = p * 2;
        float dq = dvL[nl];
        const float* xr = x + (size_t)(nd0 + nl) * K;
        float a = (c0 < K)     ? dq * xr[c0]     : 0.f;
        float bq = (c0 + 1 < K) ? dq * xr[c0 + 1] : 0.f;
        reinterpret_cast<__half2*>(x16)[(size_t)(nd0 + nl) * 16 + p] = __floats2half2_rn(a, bq);
    }
}

// Layer-1 aggregation over raw x: 8 nodes/wave (8 lanes each, uint2 = 4ch/lane),
// 8-wide edge unroll -> up to 64 row fetches in flight per wave.
__global__ void k_agg_x(const __half* __restrict__ x16, const int* __restrict__ off,
                        const u64* __restrict__ csr, const float* __restrict__ dinv,
                        float* __restrict__ agg, int n, int K) {
    int t = blockIdx.x * blockDim.x + threadIdx.x;
    int lane = threadIdx.x & 63;
    int node = ((t >> 6) << 3) + (lane >> 3);   // 8 nodes per wave
    int sub = lane & 7;                         // uint2 index (4 channels)
    if (node >= n) return;
    const uint2* xp = reinterpret_cast<const uint2*>(x16);   // 8 uint2 per row
    uint2 sv = xp[(size_t)node * 8 + sub];
    float acc0, acc1, acc2, acc3;
    {
        float2 a = __half22float2(*(const __half2*)&sv.x);
        float2 b = __half22float2(*(const __half2*)&sv.y);
        acc0 = a.x; acc1 = a.y; acc2 = b.x; acc3 = b.y;
    }
    int i = off[node], e1 = off[node + 1];
    for (; i + 7 < e1; i += 8) {
        u64 e[8]; uint2 r[8];
#pragma unroll
        for (int j = 0; j < 8; ++j) e[j] = csr[i + j];
#pragma unroll
        for (int j = 0; j < 8; ++j) r[j] = xp[(size_t)(e[j] >> 32) * 8 + sub];
#pragma unroll
        for (int j = 0; j < 8; ++j) {
            float w = __uint_as_float((unsigned)e[j]);
            float2 a = __half22float2(*(const __half2*)&r[j].x);
            float2 b = __half22float2(*(const __half2*)&r[j].y);
            acc0 = fmaf(w, a.x, acc0); acc1 = fmaf(w, a.y, acc1);
            acc2 = fmaf(w, b.x, acc2); acc3 = fmaf(w, b.y, acc3);
        }
    }
    for (; i < e1; ++i) {
        u64 e0 = csr[i];
        uint2 r = xp[(size_t)(e0 >> 32) * 8 + sub];
        float w = __uint_as_float((unsigned)e0);
        float2 a = __half22float2(*(const __half2*)&r.x);
        float2 b = __half22float2(*(const __half2*)&r.y);
        acc0 = fmaf(w, a.x, acc0); acc1 = fmaf(w, a.y, acc1);
        acc2 = fmaf(w, b.x, acc2); acc3 = fmaf(w, b.y, acc3);
    }
    int c0 = sub * 4;
    float d = dinv[node];
    float* ap = agg + (size_t)node * K + c0;
    if (c0 + 3 < K) {
        float2 o0; o0.x = d * acc0; o0.y = d * acc1;
        float2 o1; o1.x = d * acc2; o1.y = d * acc3;
        *reinterpret_cast<float2*>(ap) = o0;
        *reinterpret_cast<float2*>(ap + 2) = o1;
    } else if (c0 < K) {   // K=22: c0==20 -> last 2 channels
        float2 o; o.x = d * acc0; o.y = d * acc1;
        *reinterpret_cast<float2*>(ap) = o;
    }
}

// Fused layer-1 transform: hbuf = fp16(dinv * (relu(agg@W1 + b1) @ W2)).
template <int K1>
__global__ __launch_bounds__(256) void k_layer1_fused(const float* __restrict__ agg,
                                                      const float* __restrict__ W1,
                                                      const float* __restrict__ b1,
                                                      const float* __restrict__ W2,
                                                      const float* __restrict__ dinv,
                                                      __half* __restrict__ h, int n) {
    __shared__ float smem[HIDC * XS_STRIDE];   // phase1: agg^T tile; phase2: relu^T tile
    __shared__ float ws[HIDC * HIDC];          // phase1: W1; phase2: W2
    int tid = threadIdx.x;
    int n0 = blockIdx.x * MTILE;

    for (int i = tid; i < K1 * HIDC; i += 256) ws[i] = W1[i];
    for (int i = tid; i < MTILE * K1; i += 256) {
        int r = i / K1, k = i - r * K1;
        smem[k * XS_STRIDE + r] = (n0 + r < n) ? agg[(size_t)(n0 + r) * K1 + k] : 0.f;
    }
    __syncthreads();

    int c0 = (tid & 15) * 4;
    int m0 = (tid >> 4) * 8;
    float acc[8][4];
#pragma unroll
    for (int j = 0; j < 8; ++j)
#pragma unroll
        for (int q = 0; q < 4; ++q) acc[j][q] = 0.f;

#pragma unroll 2
    for (int k = 0; k < K1; ++k) {
        float4 a0 = *reinterpret_cast<const float4*>(&smem[k * XS_STRIDE + m0]);
        float4 a1 = *reinterpret_cast<const float4*>(&smem[k * XS_STRIDE + m0 + 4]);
        float4 b  = *reinterpret_cast<const float4*>(&ws[k * HIDC + c0]);
        float av[8] = {a0.x, a0.y, a0.z, a0.w, a1.x, a1.y, a1.z, a1.w};
        float bv[4] = {b.x, b.y, b.z, b.w};
#pragma unroll
        for (int j = 0; j < 8; ++j)
#pragma unroll
            for (int q = 0; q < 4; ++q)
                acc[j][q] = fmaf(av[j], bv[q], acc[j][q]);
    }

    float4 bb = *reinterpret_cast<const float4*>(b1 + c0);
    float bv4[4] = {bb.x, bb.y, bb.z, bb.w};
#pragma unroll
    for (int j = 0; j < 8; ++j)
#pragma unroll
        for (int q = 0; q < 4; ++q)
            acc[j][q] = fmaxf(acc[j][q] + bv4[q], 0.f);

    __syncthreads();   // phase-1 reads done; smem/ws reusable

#pragma unroll
    for (int j = 0; j < 8; ++j)
#pragma unroll
        for (int q = 0; q < 4; ++q)
            smem[(c0 + q) * XS_STRIDE + (m0 + j)] = (n0 + m0 + j < n) ? acc[j][q] : 0.f;
    for (int i = tid; i < HIDC * HIDC; i += 256) ws[i] = W2[i];
    __syncthreads();

#pragma unroll
    for (int j = 0; j < 8; ++j)
#pragma unroll
        for (int q = 0; q < 4; ++q) acc[j][q] = 0.f;

#pragma unroll 2
    for (int k = 0; k < HIDC; ++k) {
        float4 a0 = *reinterpret_cast<const float4*>(&smem[k * XS_STRIDE + m0]);
        float4 a1 = *reinterpret_cast<const float4*>(&smem[k * XS_STRIDE + m0 + 4]);
        float4 b  = *reinterpret_cast<const float4*>(&ws[k * HIDC + c0]);
        float av[8] = {a0.x, a0.y, a0.z, a0.w, a1.x, a1.y, a1.z, a1.w};
        float bv[4] = {b.x, b.y, b.z, b.w};
#pragma unroll
        for (int j = 0; j < 8; ++j)
#pragma unroll
            for (int q = 0; q < 4; ++q)
                acc[j][q] = fmaf(av[j], bv[q], acc[j][q]);
    }

#pragma unroll
    for (int j = 0; j < 8; ++j) {
        int node = n0 + m0 + j;
        if (node < n) {
            float dv = dinv[node];
            union { struct { __half2 a, b; } h2; float2 f2; } u;
            u.h2.a = __floats2half2_rn(acc[j][0] * dv, acc[j][1] * dv);
            u.h2.b = __floats2half2_rn(acc[j][2] * dv, acc[j][3] * dv);
            *reinterpret_cast<float2*>(h + (size_t)node * HIDC + c0) = u.f2;
        }
    }
}

// Layer-2 gather: 4 nodes/wave (16 lanes x uint2 = 4ch), 8-wide edge unroll
// -> 32 row fetches in flight. out = relu(dinv*(h'self + sum w*h'src) + b).
__global__ void k_gcn_gather(const __half* __restrict__ h, const int* __restrict__ off,
                             const u64* __restrict__ csr, const float* __restrict__ dinv,
                             const float* __restrict__ bias, float* __restrict__ out, int n) {
    int t = blockIdx.x * blockDim.x + threadIdx.x;
    int lane = threadIdx.x & 63;
    int node = ((t >> 6) << 2) + (lane >> 4);   // 4 nodes per wave
    int sub = lane & 15;                        // uint2 index (4 channels)
    if (node >= n) return;
    const uint2* hp = reinterpret_cast<const uint2*>(h);   // 16 uint2 per row
    float d = dinv[node];
    uint2 sv = hp[(size_t)node * 16 + sub];
    float acc0, acc1, acc2, acc3;
    {
        float2 a = __half22float2(*(const __half2*)&sv.x);
        float2 b = __half22float2(*(const __half2*)&sv.y);
        acc0 = a.x; acc1 = a.y; acc2 = b.x; acc3 = b.y;
    }
    int i = off[node], e1 = off[node + 1];
    for (; i + 7 < e1; i += 8) {
        u64 e[8]; uint2 r[8];
#pragma unroll
        for (int j = 0; j < 8; ++j) e[j] = csr[i + j];
#pragma unroll
        for (int j = 0; j < 8; ++j) r[j] = hp[(size_t)(e[j] >> 32) * 16 + sub];
#pragma unroll
        for (int j = 0; j < 8; ++j) {
            float w = __uint_as_float((unsigned)e[j]);
            float2 a = __half22float2(*(const __half2*)&r[j].x);
            float2 b = __half22float2(*(const __half2*)&r[j].y);
            acc0 = fmaf(w, a.x, acc0); acc1 = fmaf(w, a.y, acc1);
            acc2 = fmaf(w, b.x, acc2); acc3 = fmaf(w, b.y, acc3);
        }
    }
    for (; i < e1; ++i) {
        u64 e0 = csr[i];
        uint2 r = hp[(size_t)(e0 >> 32) * 16 + sub];
        float w = __uint_as_float((unsigned)e0);
        float2 a = __half22float2(*(const __half2*)&r.x);
        float2 b = __half22float2(*(const __half2*)&r.y);
        acc0 = fmaf(w, a.x, acc0); acc1 = fmaf(w, a.y, acc1);
        acc2 = fmaf(w, b.x, acc2); acc3 = fmaf(w, b.y, acc3);
    }
    int c0 = sub * 4;
    float4 bb = *reinterpret_cast<const float4*>(bias + c0);
    float4 o;
    o.x = fmaxf(fmaf(d, acc0, bb.x), 0.f);
    o.y = fmaxf(fmaf(d, acc1, bb.y), 0.f);
    o.z = fmaxf(fmaf(d, acc2, bb.z), 0.f);
    o.w = fmaxf(fmaf(d, acc3, bb.w), 0.f);
    *reinterpret_cast<float4*>(out + (size_t)node * HIDC + c0) = o;
}

// batch is sorted: segmented accumulate, flush (atomic) only on graph change.
__global__ void k_pool(const float* __restrict__ h, const int* __restrict__ batch,
                       float* __restrict__ pooled, float* __restrict__ cnt, int n) {
    int c = threadIdx.x & 63, sub = threadIdx.x >> 6;
    int n0 = blockIdx.x * 256;
    int nend = min(n0 + 256, n);
    float acc = 0.f, cacc = 0.f;
    int curb = -1;
    for (int i = n0 + sub; i < nend; i += 4) {
        int b = batch[i];
        if (b != curb) {
            if (curb >= 0) {
                atomicAdd(&pooled[curb * HIDC + c], acc);
                if (c == 0) atomicAdd(&cnt[curb], cacc);
            }
            acc = 0.f; cacc = 0.f;
            curb = b;
        }
        acc += h[(size_t)i * HIDC + c];
        cacc += 1.f;
    }
    if (curb >= 0) {
        atomicAdd(&pooled[curb * HIDC + c], acc);
        if (c == 0) atomicAdd(&cnt[curb], cacc);
    }
}

// One 64-thread block per graph: mean, fc1+relu, fc2.
__global__ void k_head(const float* __restrict__ pooled, const float* __restrict__ cnt,
                       const float* __restrict__ fw1, const float* __restrict__ fb1,
                       const float* __restrict__ fw2, const float* __restrict__ fb2,
                       float* __restrict__ out, int nclass) {
    int g = blockIdx.x;
    int j = threadIdx.x;
    __shared__ float p[HIDC], hid[HIDC];
    float c = fmaxf(cnt[g], 1.0f);
    p[j] = pooled[g * HIDC + j] / c;
    __syncthreads();
    float acc = fb1[j];
#pragma unroll 8
    for (int k = 0; k < HIDC; ++k) acc = fmaf(p[k], fw1[k * HIDC + j], acc);
    hid[j] = fmaxf(acc, 0.f);
    __syncthreads();
    if (j < nclass) {
        float o = fb2[j];
#pragma unroll 8
        for (int k = 0; k < HIDC; ++k) o = fmaf(hid[k], fw2[k * nclass + j], o);
        out[g * nclass + j] = o;
    }
}

extern "C" void kernel_launch(void* const* d_in, const int* in_sizes, int n_in,
                              void* d_out, int out_size, void* d_ws, size_t ws_size,
                              hipStream_t stream) {
    const float* x    = (const float*)d_in[0];
    const int* eidx   = (const int*)d_in[1];
    const float* ew   = (const float*)d_in[2];
    const int* batch  = (const int*)d_in[3];
    const float* W1   = (const float*)d_in[4];
    const float* b1   = (const float*)d_in[5];
    const float* W2   = (const float*)d_in[6];
    const float* b2   = (const float*)d_in[7];
    const float* fw1  = (const float*)d_in[8];
    const float* fb1  = (const float*)d_in[9];
    const float* fw2  = (const float*)d_in[10];
    const float* fb2  = (const float*)d_in[11];
    float* out = (float*)d_out;

    const int N = in_sizes[3];
    const int E = in_sizes[1] / 2;
    const int INCH = in_sizes[0] / N;          // 22
    const int NCLASS = in_sizes[11];
    const int G = out_size / NCLASS;
    const int NB = (N + SPAN - 1) >> BSHIFT;   // 391 for N=100000 (<=512 req.)

    const int* row = eidx;
    const int* col = eidx + E;

    // ---- workspace layout (8B-aligned arrays first) ----
    char* wp = (char*)d_ws;
    u64*   bedges = (u64*)wp;    wp += sizeof(u64) * E;
    u64*   csr    = (u64*)wp;    wp += sizeof(u64) * E;
    float* dinv   = (float*)wp;  wp += sizeof(float) * N;
    __half* x16   = (__half*)wp; wp += sizeof(__half) * (size_t)N * 32;
    float* agg    = (float*)wp;  wp += sizeof(float) * (size_t)N * INCH;
    __half* hbuf  = (__half*)wp; wp += sizeof(__half) * (size_t)N * HIDC;
    float* bufB   = (float*)wp;  wp += sizeof(float) * (size_t)N * HIDC;
    float* pooled = (float*)wp;  wp += sizeof(float) * (size_t)G * HIDC;
    float* cnt    = (float*)wp;  wp += sizeof(float) * G;
    int*   off    = (int*)wp;    wp += sizeof(int) * (N + 1);
    int*   bucket_cnt  = (int*)wp; wp += sizeof(int) * NBKT_MAX;
    int*   bucket_base = (int*)wp; wp += sizeof(int) * (NBKT_MAX + 1);
    int*   cursor_g    = (int*)wp; wp += sizeof(int) * NBKT_MAX;

    const int BLK = 256;
    dim3 blk(BLK);
    int gTile   = (N + MTILE - 1) / MTILE;
    int gAggX   = (N + 31) / 32;   // 8 nodes/wave * 4 waves
    int gGather = (N + 15) / 16;   // 4 nodes/wave * 4 waves
    int nInit   = max(NB, G * HIDC + G);

    // init (bucket counts + pooled/cnt zeros)
    k_init<<<(nInit + BLK - 1) / BLK, blk, 0, stream>>>(bucket_cnt, NB, pooled, G * HIDC + G);

    // CSR build via bucket partition (+ fused x16 prep)
    k_bin_count<<<(E + 8191) / 8192, blk, 0, stream>>>(col, bucket_cnt, E, NB);
    k_bucket_scan<<<1, blk, 0, stream>>>(bucket_cnt, bucket_base, cursor_g, NB, E);
    k_bin_scatter<<<(E + BCHUNK - 1) / BCHUNK, blk, 0, stream>>>(row, col, ew, cursor_g,
                                                                 bedges, E, NB);
    k_bucket_process<<<NB, blk, 0, stream>>>(bedges, bucket_base, x, csr, dinv, off, x16,
                                             N, E, NB, INCH);

    // layer 1: agg = dinv*(x16self + sum w*x16src); hbuf = fp16(dinv*(relu(agg@W1+b1)@W2))
    k_agg_x<<<gAggX, blk, 0, stream>>>(x16, off, csr, dinv, agg, N, INCH);
    k_layer1_fused<22><<<gTile, blk, 0, stream>>>(agg, W1, b1, W2, dinv, hbuf, N);

    // layer 2 gather -> bufB
    k_gcn_gather<<<gGather, blk, 0, stream>>>(hbuf, off, csr, dinv, b2, bufB, N);

    // pool + head
    k_pool<<<(N + 255) / 256, blk, 0, stream>>>(bufB, batch, pooled, cnt, N);
    k_head<<<G, dim3(64), 0, stream>>>(pooled, cnt, fw1, fb1, fw2, fb2, out, NCLASS);
}

// Round 14
// 193.157 us; speedup vs baseline: 1.0868x; 1.0038x over previous
//
#include <hip/hip_runtime.h>
#include <hip/hip_bf16.h>
#include <hip/hip_fp16.h>

// GCN forward: 2x GCNConv(relu) -> global_mean_pool -> MLP head.
// Round 14: gathers widened again — gcn_gather 8 nodes/wave (uint4 lanes,
//           64 rows in flight), agg_x 16 nodes/wave (128 in flight).
//           Tests per-wave vs CU-MSHR concurrency limit.

#define HIDC 64
#define MTILE 128
#define XS_STRIDE (MTILE + 4)
#define BSHIFT 8
#define SPAN 256          // nodes per bucket
#define NBKT_MAX 512      // requires N <= 131072
#define BCHUNK 2048       // edges per workgroup in k_bin_scatter
#define SUM_MASK ((1ULL << 48) - 1)

typedef unsigned long long u64;

// zero bucket_cnt (NB ints) + pooled/cnt (G*65 floats, contiguous)
__global__ void k_init(int* bucket_cnt, int nb, float* pooled, int npool) {
    int i = blockIdx.x * blockDim.x + threadIdx.x;
    if (i < nb) bucket_cnt[i] = 0;
    if (i < npool) pooled[i] = 0.f;
}

// per-workgroup LDS histogram of edge destinations by bucket
__global__ __launch_bounds__(256) void k_bin_count(const int* __restrict__ col,
                                                   int* bucket_cnt, int E, int NB) {
    __shared__ int hist[NBKT_MAX];
    int tid = threadIdx.x;
    for (int i = tid; i < NB; i += 256) hist[i] = 0;
    __syncthreads();
    int base = blockIdx.x * 8192;
    for (int j = 0; j < 32; ++j) {
        int e = base + j * 256 + tid;
        if (e < E) atomicAdd(&hist[col[e] >> BSHIFT], 1);
    }
    __syncthreads();
    for (int i = tid; i < NB; i += 256)
        if (hist[i]) atomicAdd(&bucket_cnt[i], hist[i]);
}

// exclusive scan of bucket counts (NB <= 512, 2 elems/thread)
__global__ void k_bucket_scan(const int* __restrict__ bucket_cnt, int* __restrict__ bucket_base,
                              int* __restrict__ cursor_g, int NB, int E) {
    __shared__ int s[256];
    int t = threadIdx.x;
    int i0 = 2 * t, i1 = 2 * t + 1;
    int v0 = (i0 < NB) ? bucket_cnt[i0] : 0;
    int v1 = (i1 < NB) ? bucket_cnt[i1] : 0;
    s[t] = v0 + v1;
    __syncthreads();
    for (int o = 1; o < 256; o <<= 1) {
        int x = (t >= o) ? s[t - o] : 0;
        __syncthreads();
        s[t] += x;
        __syncthreads();
    }
    int ex = s[t] - (v0 + v1);
    if (i0 < NB) { bucket_base[i0] = ex;      cursor_g[i0] = ex; }
    if (i1 < NB) { bucket_base[i1] = ex + v0; cursor_g[i1] = ex + v0; }
    if (t == 0) bucket_base[NB] = E;
}

// partition edges into destination buckets via LDS staging; flushes are
// contiguous runs per bucket (coalesced). packed = ew(32) | src(23) | colin(8).
__global__ __launch_bounds__(256) void k_bin_scatter(const int* __restrict__ row,
                                                     const int* __restrict__ col,
                                                     const float* __restrict__ ew,
                                                     int* cursor_g, u64* __restrict__ bedges,
                                                     int E, int NB) {
    __shared__ int hist[NBKT_MAX], binoff[NBKT_MAX], cursor[NBKT_MAX], gbase[NBKT_MAX];
    __shared__ int s[256];
    __shared__ u64 stage[BCHUNK];
    __shared__ unsigned short binid[BCHUNK];
    int tid = threadIdx.x;
    for (int i = tid; i < NB; i += 256) hist[i] = 0;
    __syncthreads();
    int base = blockIdx.x * BCHUNK;
    u64 pk[8]; int bb[8];
#pragma unroll
    for (int j = 0; j < 8; ++j) {
        int e = base + j * 256 + tid;
        if (e < E) {
            int c = col[e];
            bb[j] = c >> BSHIFT;
            pk[j] = ((u64)__float_as_uint(ew[e]) << 32) |
                    ((u64)(unsigned)row[e] << BSHIFT) | (unsigned)(c & (SPAN - 1));
            atomicAdd(&hist[bb[j]], 1);
        } else bb[j] = -1;
    }
    __syncthreads();
    {   // exclusive scan of hist[0..NB) -> binoff/cursor, 2 elems/thread
        int i0 = 2 * tid, i1 = 2 * tid + 1;
        int v0 = (i0 < NB) ? hist[i0] : 0;
        int v1 = (i1 < NB) ? hist[i1] : 0;
        s[tid] = v0 + v1;
        __syncthreads();
        for (int o = 1; o < 256; o <<= 1) {
            int x = (tid >= o) ? s[tid - o] : 0;
            __syncthreads();
            s[tid] += x;
            __syncthreads();
        }
        int ex = s[tid] - (v0 + v1);
        if (i0 < NB) { binoff[i0] = ex;      cursor[i0] = ex; }
        if (i1 < NB) { binoff[i1] = ex + v0; cursor[i1] = ex + v0; }
    }
    __syncthreads();
#pragma unroll
    for (int j = 0; j < 8; ++j)
        if (bb[j] >= 0) {
            int pos = atomicAdd(&cursor[bb[j]], 1);
            stage[pos] = pk[j];
            binid[pos] = (unsigned short)bb[j];
        }
    __syncthreads();
    for (int i = tid; i < NB; i += 256)
        if (hist[i] > 0) gbase[i] = atomicAdd(&cursor_g[i], hist[i]);
    __syncthreads();
    int total = min(BCHUNK, E - base);
    for (int i = tid; i < total; i += 256) {
        int b = binid[i];
        bedges[(size_t)gbase[b] + (i - binoff[b])] = stage[i];
    }
}

// one workgroup per bucket (SPAN=256): ONE packed u64 LDS atomic per edge for
// deg+count, scan -> CSR offsets, in-bucket scatter, dinv/off/x16 emit.
__global__ __launch_bounds__(256) void k_bucket_process(const u64* __restrict__ bedges,
                                                        const int* __restrict__ bucket_base,
                                                        const float* __restrict__ x,
                                                        u64* __restrict__ csr,
                                                        float* __restrict__ dinv,
                                                        int* __restrict__ off,
                                                        __half* __restrict__ x16,
                                                        int N, int E, int NB, int K) {
    __shared__ u64 degp[SPAN];      // Q16.32 weighted degree | count<<48
    __shared__ int cL[SPAN];
    __shared__ int offL[SPAN];
    __shared__ float dvL[SPAN];
    __shared__ int s[256];
    int b = blockIdx.x, tid = threadIdx.x;
    int ebase = bucket_base[b], ecnt = bucket_base[b + 1] - ebase;
    int nd0 = b << BSHIFT;
    int ndn = min(SPAN, N - nd0);
    degp[tid] = (1ULL << 32);   // self-loop weight 1.0, count 0
    __syncthreads();
    for (int e = tid; e < ecnt; e += 256) {
        u64 p = bedges[ebase + e];
        int colin = (int)(p & (SPAN - 1));
        float w = __uint_as_float((unsigned)(p >> 32));
        u64 add = (u64)((double)w * 4294967296.0 + 0.5) | (1ULL << 48);
        atomicAdd(&degp[colin], add);
    }
    __syncthreads();
    // exclusive scan of counts (1 elem/thread, SPAN==256)
    int cnt_t = (int)(degp[tid] >> 48);
    s[tid] = cnt_t;
    __syncthreads();
    for (int o = 1; o < 256; o <<= 1) {
        int x_ = (tid >= o) ? s[tid - o] : 0;
        __syncthreads();
        s[tid] += x_;
        __syncthreads();
    }
    int ex = s[tid] - cnt_t;
    offL[tid] = ex;
    cL[tid] = ex;
    float dv = rsqrtf((float)((double)(degp[tid] & SUM_MASK) * 2.3283064365386963e-10));
    dvL[tid] = dv;
    if (tid < ndn) {
        dinv[nd0 + tid] = dv;
        off[nd0 + tid] = ebase + ex;
    }
    if (b == NB - 1 && tid == 0) off[N] = E;
    __syncthreads();
    // CSR scatter within bucket (L2-resident region)
    for (int e = tid; e < ecnt; e += 256) {
        u64 p = bedges[ebase + e];
        int colin = (int)(p & (SPAN - 1));
        int src = (int)((p >> BSHIFT) & 0x7FFFFF);   // 23 bits
        int slot = atomicAdd(&cL[colin], 1);
        csr[(size_t)ebase + slot] = ((u64)(unsigned)src << 32) | (unsigned)(p >> 32);
    }
    // fused prep: x16[node][32] = fp16(dinv*x[node][0..K)), rest zero (64B rows)
    for (int i = tid; i < ndn * 16; i += 256) {
        int nl = i >> 4, p = i & 15, c0 = p * 2;
        float dq = dvL[nl];
        const float* xr = x + (size_t)(nd0 + nl) * K;
        float a = (c0 < K)     ? dq * xr[c0]     : 0.f;
        float bq = (c0 + 1 < K) ? dq * xr[c0 + 1] : 0.f;
        reinterpret_cast<__half2*>(x16)[(size_t)(nd0 + nl) * 16 + p] = __floats2half2_rn(a, bq);
    }
}

// Layer-1 aggregation: 16 nodes/wave (4 lanes each, uint4 = 8ch/lane),
// 8-wide edge unroll -> up to 128 row fetches in flight per wave.
__global__ void k_agg_x(const __half* __restrict__ x16, const int* __restrict__ off,
                        const u64* __restrict__ csr, const float* __restrict__ dinv,
                        float* __restrict__ agg, int n, int K) {
    int t = blockIdx.x * blockDim.x + threadIdx.x;
    int lane = threadIdx.x & 63;
    int node = ((t >> 6) << 4) + (lane >> 2);   // 16 nodes per wave
    int sub = lane & 3;                         // uint4 index (8 channels)
    if (node >= n) return;
    const uint4* xp = reinterpret_cast<const uint4*>(x16);   // 4 uint4 per row
    float acc[8];
    {
        uint4 sv = xp[(size_t)node * 4 + sub];
        const __half2* q = reinterpret_cast<const __half2*>(&sv);
#pragma unroll
        for (int k = 0; k < 4; ++k) {
            float2 a = __half22float2(q[k]);
            acc[2 * k] = a.x; acc[2 * k + 1] = a.y;
        }
    }
    int i = off[node], e1 = off[node + 1];
    for (; i + 7 < e1; i += 8) {
        u64 e[8]; uint4 r[8];
#pragma unroll
        for (int j = 0; j < 8; ++j) e[j] = csr[i + j];
#pragma unroll
        for (int j = 0; j < 8; ++j) r[j] = xp[(size_t)(e[j] >> 32) * 4 + sub];
#pragma unroll
        for (int j = 0; j < 8; ++j) {
            float w = __uint_as_float((unsigned)e[j]);
            const __half2* q = reinterpret_cast<const __half2*>(&r[j]);
#pragma unroll
            for (int k = 0; k < 4; ++k) {
                float2 a = __half22float2(q[k]);
                acc[2 * k] = fmaf(w, a.x, acc[2 * k]);
                acc[2 * k + 1] = fmaf(w, a.y, acc[2 * k + 1]);
            }
        }
    }
    for (; i < e1; ++i) {
        u64 e0 = csr[i];
        uint4 r = xp[(size_t)(e0 >> 32) * 4 + sub];
        float w = __uint_as_float((unsigned)e0);
        const __half2* q = reinterpret_cast<const __half2*>(&r);
#pragma unroll
        for (int k = 0; k < 4; ++k) {
            float2 a = __half22float2(q[k]);
            acc[2 * k] = fmaf(w, a.x, acc[2 * k]);
            acc[2 * k + 1] = fmaf(w, a.y, acc[2 * k + 1]);
        }
    }
    int c0 = sub * 8;
    float d = dinv[node];
    float* ap = agg + (size_t)node * K;
#pragma unroll
    for (int k = 0; k < 4; ++k) {
        int c = c0 + 2 * k;
        if (c + 1 < K) {        // K even: pairs never straddle; 8B-aligned stores
            float2 o; o.x = d * acc[2 * k]; o.y = d * acc[2 * k + 1];
            *reinterpret_cast<float2*>(ap + c) = o;
        }
    }
}

// Fused layer-1 transform: hbuf = fp16(dinv * (relu(agg@W1 + b1) @ W2)).
template <int K1>
__global__ __launch_bounds__(256) void k_layer1_fused(const float* __restrict__ agg,
                                                      const float* __restrict__ W1,
                                                      const float* __restrict__ b1,
                                                      const float* __restrict__ W2,
                                                      const float* __restrict__ dinv,
                                                      __half* __restrict__ h, int n) {
    __shared__ float smem[HIDC * XS_STRIDE];   // phase1: agg^T tile; phase2: relu^T tile
    __shared__ float ws[HIDC * HIDC];          // phase1: W1; phase2: W2
    int tid = threadIdx.x;
    int n0 = blockIdx.x * MTILE;

    for (int i = tid; i < K1 * HIDC; i += 256) ws[i] = W1[i];
    for (int i = tid; i < MTILE * K1; i += 256) {
        int r = i / K1, k = i - r * K1;
        smem[k * XS_STRIDE + r] = (n0 + r < n) ? agg[(size_t)(n0 + r) * K1 + k] : 0.f;
    }
    __syncthreads();

    int c0 = (tid & 15) * 4;
    int m0 = (tid >> 4) * 8;
    float acc[8][4];
#pragma unroll
    for (int j = 0; j < 8; ++j)
#pragma unroll
        for (int q = 0; q < 4; ++q) acc[j][q] = 0.f;

#pragma unroll 2
    for (int k = 0; k < K1; ++k) {
        float4 a0 = *reinterpret_cast<const float4*>(&smem[k * XS_STRIDE + m0]);
        float4 a1 = *reinterpret_cast<const float4*>(&smem[k * XS_STRIDE + m0 + 4]);
        float4 b  = *reinterpret_cast<const float4*>(&ws[k * HIDC + c0]);
        float av[8] = {a0.x, a0.y, a0.z, a0.w, a1.x, a1.y, a1.z, a1.w};
        float bv[4] = {b.x, b.y, b.z, b.w};
#pragma unroll
        for (int j = 0; j < 8; ++j)
#pragma unroll
            for (int q = 0; q < 4; ++q)
                acc[j][q] = fmaf(av[j], bv[q], acc[j][q]);
    }

    float4 bb = *reinterpret_cast<const float4*>(b1 + c0);
    float bv4[4] = {bb.x, bb.y, bb.z, bb.w};
#pragma unroll
    for (int j = 0; j < 8; ++j)
#pragma unroll
        for (int q = 0; q < 4; ++q)
            acc[j][q] = fmaxf(acc[j][q] + bv4[q], 0.f);

    __syncthreads();   // phase-1 reads done; smem/ws reusable

#pragma unroll
    for (int j = 0; j < 8; ++j)
#pragma unroll
        for (int q = 0; q < 4; ++q)
            smem[(c0 + q) * XS_STRIDE + (m0 + j)] = (n0 + m0 + j < n) ? acc[j][q] : 0.f;
    for (int i = tid; i < HIDC * HIDC; i += 256) ws[i] = W2[i];
    __syncthreads();

#pragma unroll
    for (int j = 0; j < 8; ++j)
#pragma unroll
        for (int q = 0; q < 4; ++q) acc[j][q] = 0.f;

#pragma unroll 2
    for (int k = 0; k < HIDC; ++k) {
        float4 a0 = *reinterpret_cast<const float4*>(&smem[k * XS_STRIDE + m0]);
        float4 a1 = *reinterpret_cast<const float4*>(&smem[k * XS_STRIDE + m0 + 4]);
        float4 b  = *reinterpret_cast<const float4*>(&ws[k * HIDC + c0]);
        float av[8] = {a0.x, a0.y, a0.z, a0.w, a1.x, a1.y, a1.z, a1.w};
        float bv[4] = {b.x, b.y, b.z, b.w};
#pragma unroll
        for (int j = 0; j < 8; ++j)
#pragma unroll
            for (int q = 0; q < 4; ++q)
                acc[j][q] = fmaf(av[j], bv[q], acc[j][q]);
    }

#pragma unroll
    for (int j = 0; j < 8; ++j) {
        int node = n0 + m0 + j;
        if (node < n) {
            float dv = dinv[node];
            union { struct { __half2 a, b; } h2; float2 f2; } u;
            u.h2.a = __floats2half2_rn(acc[j][0] * dv, acc[j][1] * dv);
            u.h2.b = __floats2half2_rn(acc[j][2] * dv, acc[j][3] * dv);
            *reinterpret_cast<float2*>(h + (size_t)node * HIDC + c0) = u.f2;
        }
    }
}

// Layer-2 gather: 8 nodes/wave (8 lanes x uint4 = 8ch), 8-wide edge unroll
// -> 64 row fetches in flight. out = relu(dinv*(h'self + sum w*h'src) + b).
__global__ void k_gcn_gather(const __half* __restrict__ h, const int* __restrict__ off,
                             const u64* __restrict__ csr, const float* __restrict__ dinv,
                             const float* __restrict__ bias, float* __restrict__ out, int n) {
    int t = blockIdx.x * blockDim.x + threadIdx.x;
    int lane = threadIdx.x & 63;
    int node = ((t >> 6) << 3) + (lane >> 3);   // 8 nodes per wave
    int sub = lane & 7;                         // uint4 index (8 channels)
    if (node >= n) return;
    const uint4* hp = reinterpret_cast<const uint4*>(h);   // 8 uint4 per row
    float d = dinv[node];
    float acc[8];
    {
        uint4 sv = hp[(size_t)node * 8 + sub];
        const __half2* q = reinterpret_cast<const __half2*>(&sv);
#pragma unroll
        for (int k = 0; k < 4; ++k) {
            float2 a = __half22float2(q[k]);
            acc[2 * k] = a.x; acc[2 * k + 1] = a.y;
        }
    }
    int i = off[node], e1 = off[node + 1];
    for (; i + 7 < e1; i += 8) {
        u64 e[8]; uint4 r[8];
#pragma unroll
        for (int j = 0; j < 8; ++j) e[j] = csr[i + j];
#pragma unroll
        for (int j = 0; j < 8; ++j) r[j] = hp[(size_t)(e[j] >> 32) * 8 + sub];
#pragma unroll
        for (int j = 0; j < 8; ++j) {
            float w = __uint_as_float((unsigned)e[j]);
            const __half2* q = reinterpret_cast<const __half2*>(&r[j]);
#pragma unroll
            for (int k = 0; k < 4; ++k) {
                float2 a = __half22float2(q[k]);
                acc[2 * k] = fmaf(w, a.x, acc[2 * k]);
                acc[2 * k + 1] = fmaf(w, a.y, acc[2 * k + 1]);
            }
        }
    }
    for (; i < e1; ++i) {
        u64 e0 = csr[i];
        uint4 r = hp[(size_t)(e0 >> 32) * 8 + sub];
        float w = __uint_as_float((unsigned)e0);
        const __half2* q = reinterpret_cast<const __half2*>(&r);
#pragma unroll
        for (int k = 0; k < 4; ++k) {
            float2 a = __half22float2(q[k]);
            acc[2 * k] = fmaf(w, a.x, acc[2 * k]);
            acc[2 * k + 1] = fmaf(w, a.y, acc[2 * k + 1]);
        }
    }
    int c0 = sub * 8;
    float4 b0 = *reinterpret_cast<const float4*>(bias + c0);
    float4 b1v = *reinterpret_cast<const float4*>(bias + c0 + 4);
    float4 o0, o1;
    o0.x = fmaxf(fmaf(d, acc[0], b0.x), 0.f);
    o0.y = fmaxf(fmaf(d, acc[1], b0.y), 0.f);
    o0.z = fmaxf(fmaf(d, acc[2], b0.z), 0.f);
    o0.w = fmaxf(fmaf(d, acc[3], b0.w), 0.f);
    o1.x = fmaxf(fmaf(d, acc[4], b1v.x), 0.f);
    o1.y = fmaxf(fmaf(d, acc[5], b1v.y), 0.f);
    o1.z = fmaxf(fmaf(d, acc[6], b1v.z), 0.f);
    o1.w = fmaxf(fmaf(d, acc[7], b1v.w), 0.f);
    *reinterpret_cast<float4*>(out + (size_t)node * HIDC + c0) = o0;
    *reinterpret_cast<float4*>(out + (size_t)node * HIDC + c0 + 4) = o1;
}

// batch is sorted: segmented accumulate, flush (atomic) only on graph change.
__global__ void k_pool(const float* __restrict__ h, const int* __restrict__ batch,
                       float* __restrict__ pooled, float* __restrict__ cnt, int n) {
    int c = threadIdx.x & 63, sub = threadIdx.x >> 6;
    int n0 = blockIdx.x * 256;
    int nend = min(n0 + 256, n);
    float acc = 0.f, cacc = 0.f;
    int curb = -1;
    for (int i = n0 + sub; i < nend; i += 4) {
        int b = batch[i];
        if (b != curb) {
            if (curb >= 0) {
                atomicAdd(&pooled[curb * HIDC + c], acc);
                if (c == 0) atomicAdd(&cnt[curb], cacc);
            }
            acc = 0.f; cacc = 0.f;
            curb = b;
        }
        acc += h[(size_t)i * HIDC + c];
        cacc += 1.f;
    }
    if (curb >= 0) {
        atomicAdd(&pooled[curb * HIDC + c], acc);
        if (c == 0) atomicAdd(&cnt[curb], cacc);
    }
}

// One 64-thread block per graph: mean, fc1+relu, fc2.
__global__ void k_head(const float* __restrict__ pooled, const float* __restrict__ cnt,
                       const float* __restrict__ fw1, const float* __restrict__ fb1,
                       const float* __restrict__ fw2, const float* __restrict__ fb2,
                       float* __restrict__ out, int nclass) {
    int g = blockIdx.x;
    int j = threadIdx.x;
    __shared__ float p[HIDC], hid[HIDC];
    float c = fmaxf(cnt[g], 1.0f);
    p[j] = pooled[g * HIDC + j] / c;
    __syncthreads();
    float acc = fb1[j];
#pragma unroll 8
    for (int k = 0; k < HIDC; ++k) acc = fmaf(p[k], fw1[k * HIDC + j], acc);
    hid[j] = fmaxf(acc, 0.f);
    __syncthreads();
    if (j < nclass) {
        float o = fb2[j];
#pragma unroll 8
        for (int k = 0; k < HIDC; ++k) o = fmaf(hid[k], fw2[k * nclass + j], o);
        out[g * nclass + j] = o;
    }
}

extern "C" void kernel_launch(void* const* d_in, const int* in_sizes, int n_in,
                              void* d_out, int out_size, void* d_ws, size_t ws_size,
                              hipStream_t stream) {
    const float* x    = (const float*)d_in[0];
    const int* eidx   = (const int*)d_in[1];
    const float* ew   = (const float*)d_in[2];
    const int* batch  = (const int*)d_in[3];
    const float* W1   = (const float*)d_in[4];
    const float* b1   = (const float*)d_in[5];
    const float* W2   = (const float*)d_in[6];
    const float* b2   = (const float*)d_in[7];
    const float* fw1  = (const float*)d_in[8];
    const float* fb1  = (const float*)d_in[9];
    const float* fw2  = (const float*)d_in[10];
    const float* fb2  = (const float*)d_in[11];
    float* out = (float*)d_out;

    const int N = in_sizes[3];
    const int E = in_sizes[1] / 2;
    const int INCH = in_sizes[0] / N;          // 22
    const int NCLASS = in_sizes[11];
    const int G = out_size / NCLASS;
    const int NB = (N + SPAN - 1) >> BSHIFT;   // 391 for N=100000 (<=512 req.)

    const int* row = eidx;
    const int* col = eidx + E;

    // ---- workspace layout (8B-aligned arrays first) ----
    char* wp = (char*)d_ws;
    u64*   bedges = (u64*)wp;    wp += sizeof(u64) * E;
    u64*   csr    = (u64*)wp;    wp += sizeof(u64) * E;
    float* dinv   = (float*)wp;  wp += sizeof(float) * N;
    __half* x16   = (__half*)wp; wp += sizeof(__half) * (size_t)N * 32;
    float* agg    = (float*)wp;  wp += sizeof(float) * (size_t)N * INCH;
    __half* hbuf  = (__half*)wp; wp += sizeof(__half) * (size_t)N * HIDC;
    float* bufB   = (float*)wp;  wp += sizeof(float) * (size_t)N * HIDC;
    float* pooled = (float*)wp;  wp += sizeof(float) * (size_t)G * HIDC;
    float* cnt    = (float*)wp;  wp += sizeof(float) * G;
    int*   off    = (int*)wp;    wp += sizeof(int) * (N + 1);
    int*   bucket_cnt  = (int*)wp; wp += sizeof(int) * NBKT_MAX;
    int*   bucket_base = (int*)wp; wp += sizeof(int) * (NBKT_MAX + 1);
    int*   cursor_g    = (int*)wp; wp += sizeof(int) * NBKT_MAX;

    const int BLK = 256;
    dim3 blk(BLK);
    int gTile   = (N + MTILE - 1) / MTILE;
    int gAggX   = (N + 63) / 64;   // 16 nodes/wave * 4 waves
    int gGather = (N + 31) / 32;   // 8 nodes/wave * 4 waves
    int nInit   = max(NB, G * HIDC + G);

    // init (bucket counts + pooled/cnt zeros)
    k_init<<<(nInit + BLK - 1) / BLK, blk, 0, stream>>>(bucket_cnt, NB, pooled, G * HIDC + G);

    // CSR build via bucket partition (+ fused x16 prep)
    k_bin_count<<<(E + 8191) / 8192, blk, 0, stream>>>(col, bucket_cnt, E, NB);
    k_bucket_scan<<<1, blk, 0, stream>>>(bucket_cnt, bucket_base, cursor_g, NB, E);
    k_bin_scatter<<<(E + BCHUNK - 1) / BCHUNK, blk, 0, stream>>>(row, col, ew, cursor_g,
                                                                 bedges, E, NB);
    k_bucket_process<<<NB, blk, 0, stream>>>(bedges, bucket_base, x, csr, dinv, off, x16,
                                             N, E, NB, INCH);

    // layer 1: agg = dinv*(x16self + sum w*x16src); hbuf = fp16(dinv*(relu(agg@W1+b1)@W2))
    k_agg_x<<<gAggX, blk, 0, stream>>>(x16, off, csr, dinv, agg, N, INCH);
    k_layer1_fused<22><<<gTile, blk, 0, stream>>>(agg, W1, b1, W2, dinv, hbuf, N);

    // layer 2 gather -> bufB
    k_gcn_gather<<<gGather, blk, 0, stream>>>(hbuf, off, csr, dinv, b2, bufB, N);

    // pool + head
    k_pool<<<(N + 255) / 256, blk, 0, stream>>>(bufB, batch, pooled, cnt, N);
    k_head<<<G, dim3(64), 0, stream>>>(pooled, cnt, fw1, fb1, fw2, fb2, out, NCLASS);
}